// Round 5
// baseline (477.937 us; speedup 1.0000x reference)
//
#include <hip/hip_runtime.h>
#include <hip/hip_bf16.h>
#include <stdint.h>
#include <stddef.h>

typedef __attribute__((ext_vector_type(8))) short short8v;   // 8 bf16 = 4 VGPR
typedef __attribute__((ext_vector_type(4))) float f32x4;
typedef __attribute__((ext_vector_type(16))) float f32x16;
typedef unsigned short us;

__device__ __forceinline__ float bf2f(unsigned short u) {
    return __uint_as_float(((unsigned int)u) << 16);
}
__device__ __forceinline__ unsigned short f2bf(float f) {
    unsigned int x = __float_as_uint(f);
    x += 0x7fffu + ((x >> 16) & 1u);   // RNE
    return (unsigned short)(x >> 16);
}
// packed f32x2 -> bf16x2 (hardware RNE), 1 instruction
__device__ __forceinline__ unsigned int cvtpk(float lo, float hi) {
    unsigned int r;
    asm("v_cvt_pk_bf16_f32 %0, %1, %2" : "=v"(r) : "v"(lo), "v"(hi));
    return r;
}

#define NTOK 8192      // b*n
#define DM   1024
#define NPROJ 3072     // q512 | k512 | v1024 | g1024
#define SEQ  4096
#define NCHUNK 64
#define SCQ 0.08838834764831845f   // 128^-0.5

#define GLDS16(g, l) __builtin_amdgcn_global_load_lds( \
    (const __attribute__((address_space(1))) void*)(g), \
    (__attribute__((address_space(3))) void*)(l), 16, 0, 0)

__device__ __forceinline__ void bar_lgkm() {
    asm volatile("s_waitcnt lgkmcnt(0)" ::: "memory");
    __builtin_amdgcn_s_barrier();
    __builtin_amdgcn_sched_barrier(0);
}

// chunk_pre swizzles (unchanged from round 3/4)
__device__ __forceinline__ int sw16(int row, int k) {
    int u = k >> 3;
    int us_ = (u & 8) | ((u ^ row) & 7);
    return row * 128 + us_ * 8 + (k & 7);
}
__device__ __forceinline__ int sw8(int row, int k) {
    int u = k >> 3;
    int us_ = (u ^ row) & 7;
    return row * 64 + us_ * 8 + (k & 7);
}
// scan swizzles: full XOR
__device__ __forceinline__ int swST(int row, int k) {   // [64][128]
    int u = k >> 3;
    return row * 128 + ((u ^ row) & 15) * 8 + (k & 7);
}
__device__ __forceinline__ int swDT(int row, int k) {   // [64][64]
    int u = k >> 3;
    return row * 64 + ((u ^ row) & 7) * 8 + (k & 7);
}

// ---------------- elementwise / conversion ----------------
__global__ void convert_x(const float* __restrict__ x, us* __restrict__ xb, int n4) {
    int i = blockIdx.x * 256 + threadIdx.x;
    if (i >= n4) return;
    float4 v = ((const float4*)x)[i];
    uint2 o;
    o.x = cvtpk(v.x, v.y);
    o.y = cvtpk(v.z, v.w);
    ((uint2*)xb)[i] = o;
}

// dst[n][k] = bf16(src[k][n]); src K x N f32, dst N x K bf16 (row stride K=1024)
__global__ __launch_bounds__(256) void transpose_w(const float* __restrict__ src,
                                                   us* __restrict__ dst, int K, int N) {
    __shared__ float tl[64][65];
    int k0 = blockIdx.y * 64, n0 = blockIdx.x * 64;
    int tid = threadIdx.x;
    int tr = tid >> 6, tc = tid & 63;
    #pragma unroll
    for (int i = 0; i < 16; i++) {
        int kk = 4 * i + tr;
        tl[kk][tc] = src[(size_t)(k0 + kk) * N + n0 + tc];
    }
    __syncthreads();
    int n = tid >> 2, seg = (tid & 3) * 16;
    short8v a, b;
    #pragma unroll
    for (int e = 0; e < 8; e++) {
        a[e] = (short)f2bf(tl[seg + e][n]);
        b[e] = (short)f2bf(tl[seg + 8 + e][n]);
    }
    us* d = dst + (size_t)(n0 + n) * K + k0 + seg;
    *(short8v*)d = a;
    *(short8v*)(d + 8) = b;
}

// beta: block handles 16 tokens; 16 seg-threads per token, float4 loads.
__global__ __launch_bounds__(256) void beta_kernel(const float* __restrict__ x,
                                                   const float* __restrict__ Wb,
                                                   float* __restrict__ beta) {
    __shared__ float part[16][16][4];
    int tl = threadIdx.x >> 4, sg = threadIdx.x & 15;
    int tok = blockIdx.x * 16 + tl;
    const float4* xr = (const float4*)(x + (size_t)tok * DM);
    const float4* wb = (const float4*)Wb;
    float s0 = 0.f, s1 = 0.f, s2 = 0.f, s3 = 0.f;
    #pragma unroll
    for (int it = 0; it < 16; it++) {
        int f = it * 16 + sg;
        float4 xv = xr[f];
        float4 w0 = wb[4 * f + 0], w1 = wb[4 * f + 1], w2 = wb[4 * f + 2], w3 = wb[4 * f + 3];
        s0 += xv.x * w0.x + xv.y * w1.x + xv.z * w2.x + xv.w * w3.x;
        s1 += xv.x * w0.y + xv.y * w1.y + xv.z * w2.y + xv.w * w3.y;
        s2 += xv.x * w0.z + xv.y * w1.z + xv.z * w2.z + xv.w * w3.z;
        s3 += xv.x * w0.w + xv.y * w1.w + xv.z * w2.w + xv.w * w3.w;
    }
    part[tl][sg][0] = s0; part[tl][sg][1] = s1; part[tl][sg][2] = s2; part[tl][sg][3] = s3;
    __syncthreads();
    if (threadIdx.x < 64) {
        int tl2 = threadIdx.x >> 2, h = threadIdx.x & 3;
        float s = 0.f;
        #pragma unroll
        for (int g = 0; g < 16; g++) s += part[tl2][g][h];
        beta[(size_t)(blockIdx.x * 16 + tl2) * 4 + h] = 1.f / (1.f + __expf(-s));
    }
}

// ---------------- bf16 MFMA GEMM: C[M][N] = A[M][K] * BT[N][K]^T ----------------
template<int OUT_F32>
__global__ __launch_bounds__(256) void gemm_bt(
    const us* __restrict__ A, const us* __restrict__ BT,
    void* __restrict__ C, int M, int N, int K)
{
    __shared__ us As[128][32];
    __shared__ us Bs[128][32];
    int tid = threadIdx.x;
    int wave = tid >> 6, lane = tid & 63;
    int wr = (wave >> 1) * 64, wc = (wave & 1) * 64;
    int fr = lane & 15, fq = lane >> 4;
    // bijective XCD swizzle (grid sizes are multiples of 8)
    int nbx = gridDim.x, nwg = nbx * gridDim.y;
    int wg = blockIdx.y * nbx + blockIdx.x;
    int cpx = nwg >> 3;
    wg = (wg & 7) * cpx + (wg >> 3);
    int m0 = (wg % nbx) * 128, n0 = (wg / nbx) * 128;

    f32x4 acc[4][4];
    #pragma unroll
    for (int i = 0; i < 4; i++)
        #pragma unroll
        for (int j = 0; j < 4; j++) acc[i][j] = (f32x4){0.f, 0.f, 0.f, 0.f};

    int srow = (lane >> 2);
    int sce  = (lane & 3) * 8;

    for (int k0 = 0; k0 < K; k0 += 32) {
        #pragma unroll
        for (int i = 0; i < 2; i++) {
            int seg = wave * 2 + i;
            int row = seg * 16 + srow;
            GLDS16(&A[(size_t)(m0 + row) * K + k0 + sce], &As[0][0] + seg * 512);
            GLDS16(&BT[(size_t)(n0 + row) * K + k0 + sce], &Bs[0][0] + seg * 512);
        }
        __syncthreads();
        short8v a[4], b[4];
        #pragma unroll
        for (int i = 0; i < 4; i++) {
            a[i] = *(const short8v*)&As[wr + i * 16 + fr][fq * 8];
            b[i] = *(const short8v*)&Bs[wc + i * 16 + fr][fq * 8];
        }
        #pragma unroll
        for (int i = 0; i < 4; i++)
            #pragma unroll
            for (int j = 0; j < 4; j++)
                acc[i][j] = __builtin_amdgcn_mfma_f32_16x16x32_bf16(a[i], b[j], acc[i][j], 0, 0, 0);
        __syncthreads();
    }
    #pragma unroll
    for (int i = 0; i < 4; i++)
        #pragma unroll
        for (int j = 0; j < 4; j++)
            #pragma unroll
            for (int t = 0; t < 4; t++) {
                int row = m0 + wr + i * 16 + fq * 4 + t;
                int col = n0 + wc + j * 16 + fr;
                float val = acc[i][j][t];
                if (OUT_F32) ((float*)C)[(size_t)row * N + col] = val;
                else ((us*)C)[(size_t)row * N + col] = f2bf(val);
            }
}

// ---------------- per-chunk precompute (unchanged from round 4) ----------------
__global__ __launch_bounds__(256) void chunk_pre(
    const us* __restrict__ QKVG, const float* __restrict__ beta,
    us* __restrict__ Wbuf, us* __restrict__ Ubuf,
    us* __restrict__ Pbuf, us* __restrict__ KTbuf)
{
    __shared__ us Ks[8192];
    __shared__ us KTs[8192];
    __shared__ us VT[8192];
    __shared__ us Tb[4096];
    __shared__ float Af[64][64];
    __shared__ float betas[64];

    int c = blockIdx.x, bh = blockIdx.y;
    int b = bh >> 2, h = bh & 3;
    int tid = threadIdx.x;
    int wv = tid >> 6, ln = tid & 63;
    int fr = ln & 15, fq = ln >> 4;
    int tok0 = b * SEQ + c * 64;
    size_t cb = (size_t)bh * NCHUNK + c;

    #pragma unroll
    for (int r = 0; r < 4; r++) {
        int idx = tid + 256 * r;
        int t = idx >> 4, u = idx & 15;
        short8v kv = *(const short8v*)(QKVG + (size_t)(tok0 + t) * NPROJ + 512 + h * 128 + u * 8);
        *(short8v*)(Ks + sw16(t, u * 8)) = kv;
    }
    if (tid < 64) betas[tid] = beta[(size_t)(tok0 + tid) * 4 + h];
    __syncthreads();

    {
        int t = tid >> 2, p = tid & 3;
        short8v v[4];
        float ss = 0.f;
        #pragma unroll
        for (int uu = 0; uu < 4; uu++) {
            v[uu] = *(const short8v*)(Ks + sw16(t, (p * 4 + uu) * 8));
            #pragma unroll
            for (int e = 0; e < 8; e++) {
                float f = bf2f((unsigned short)v[uu][e]);
                ss += f * f;
            }
        }
        ss += __shfl_xor(ss, 1);
        ss += __shfl_xor(ss, 2);
        float rn = rsqrtf(ss + 1e-12f);
        #pragma unroll
        for (int uu = 0; uu < 4; uu++) {
            short8v o;
            #pragma unroll
            for (int e = 0; e < 8; e++)
                o[e] = (short)f2bf(bf2f((unsigned short)v[uu][e]) * rn);
            *(short8v*)(Ks + sw16(t, (p * 4 + uu) * 8)) = o;
        }
    }
    __syncthreads();

    {
        f32x4 aacc[4];
        #pragma unroll
        for (int jt = 0; jt < 4; jt++) aacc[jt] = (f32x4){0.f, 0.f, 0.f, 0.f};
        #pragma unroll
        for (int ks = 0; ks < 4; ks++) {
            short8v ak = *(const short8v*)(Ks + sw16(16 * wv + fr, 32 * ks + 8 * fq));
            #pragma unroll
            for (int jt = 0; jt < 4; jt++) {
                short8v bk = *(const short8v*)(Ks + sw16(16 * jt + fr, 32 * ks + 8 * fq));
                aacc[jt] = __builtin_amdgcn_mfma_f32_16x16x32_bf16(ak, bk, aacc[jt], 0, 0, 0);
            }
        }
        #pragma unroll
        for (int jt = 0; jt < 4; jt++)
            #pragma unroll
            for (int r = 0; r < 4; r++) {
                int t = 16 * wv + 4 * fq + r, s = 16 * jt + fr;
                if (s < t) Af[t][s] = betas[t] * aacc[jt][r];
            }
    }
    __syncthreads();

    if (wv == 0) {
        int cc = ln;
        for (int t = 1; t < 64; t++) {
            float aown = Af[t][cc];
            float acc = 0.f;
            for (int s = cc + 1; s < t; s++)
                acc += Af[t][s] * Af[s][cc];
            if (cc < t) Af[t][cc] = -aown - acc;
        }
    } else {
        int q = tid - 64;
        for (int g = q; g < 1024; g += 192) {
            int t = g >> 4, u = g & 15;
            short8v kv = *(const short8v*)(Ks + sw16(t, u * 8));
            #pragma unroll
            for (int e = 0; e < 8; e++)
                KTs[sw8(u * 8 + e, t)] = (unsigned short)kv[e];
        }
        for (int g = q; g < 1024; g += 192) {
            int t = g >> 4, jg = g & 15;
            short8v vv = *(const short8v*)(QKVG + (size_t)(tok0 + t) * NPROJ + 1024 + h * 256 + jg * 8);
            #pragma unroll
            for (int e = 0; e < 8; e++)
                VT[sw8(jg * 8 + e, t)] = (unsigned short)vv[e];
        }
    }
    __syncthreads();

    {
        f32x4 pacc[4];
        #pragma unroll
        for (int jt = 0; jt < 4; jt++) pacc[jt] = (f32x4){0.f, 0.f, 0.f, 0.f};
        #pragma unroll
        for (int ks = 0; ks < 4; ks++) {
            short8v aq = *(const short8v*)(QKVG + (size_t)(tok0 + 16 * wv + fr) * NPROJ + h * 128 + ks * 32 + fq * 8);
            #pragma unroll
            for (int jt = 0; jt < 4; jt++) {
                short8v bk = *(const short8v*)(Ks + sw16(16 * jt + fr, 32 * ks + 8 * fq));
                pacc[jt] = __builtin_amdgcn_mfma_f32_16x16x32_bf16(aq, bk, pacc[jt], 0, 0, 0);
            }
        }
        #pragma unroll
        for (int jt = 0; jt < 4; jt++)
            #pragma unroll
            for (int r = 0; r < 4; r++) {
                int t = 16 * wv + 4 * fq + r, s = 16 * jt + fr;
                float val = (s <= t) ? pacc[jt][r] * SCQ : 0.f;
                Pbuf[cb * 4096 + t * 64 + s] = f2bf(val);
            }
        #pragma unroll
        for (int i = 0; i < 16; i++) {
            int idx = tid + 256 * i;
            int t = idx >> 6, s = idx & 63;
            float tv = (s < t) ? Af[t][s] : (s == t ? 1.f : 0.f);
            Tb[sw8(t, s)] = f2bf(tv * betas[s]);
        }
        #pragma unroll
        for (int i = 0; i < 4; i++) {
            int idx = tid + 256 * i;
            int d = idx >> 3, ug = idx & 7;
            *(short8v*)(KTbuf + cb * 8192 + (size_t)d * 64 + ug * 8) =
                *(const short8v*)(KTs + sw8(d, ug * 8));
        }
    }
    __syncthreads();

    {
        f32x4 wacc[8], uacc[8];
        #pragma unroll
        for (int jt = 0; jt < 8; jt++) {
            wacc[jt] = (f32x4){0.f, 0.f, 0.f, 0.f};
            uacc[jt] = (f32x4){0.f, 0.f, 0.f, 0.f};
        }
        #pragma unroll
        for (int ks = 0; ks < 2; ks++) {
            short8v at = *(const short8v*)(Tb + sw8(16 * wv + fr, 32 * ks + 8 * fq));
            #pragma unroll
            for (int jt = 0; jt < 8; jt++) {
                short8v bk = *(const short8v*)(KTs + sw8(16 * jt + fr, 32 * ks + 8 * fq));
                wacc[jt] = __builtin_amdgcn_mfma_f32_16x16x32_bf16(at, bk, wacc[jt], 0, 0, 0);
                short8v bv = *(const short8v*)(VT + sw8(16 * jt + fr, 32 * ks + 8 * fq));
                uacc[jt] = __builtin_amdgcn_mfma_f32_16x16x32_bf16(at, bv, uacc[jt], 0, 0, 0);
            }
        }
        #pragma unroll
        for (int jt = 0; jt < 8; jt++)
            #pragma unroll
            for (int r = 0; r < 4; r++) {
                int t = 16 * wv + 4 * fq + r, d = 16 * jt + fr;
                Wbuf[cb * 8192 + (size_t)t * 128 + d] = f2bf(-wacc[jt][r]);   // negated
                Ubuf[cb * 16384 + (size_t)t * 256 + d] = f2bf(uacc[jt][r]);
            }
    }
    __syncthreads();

    #pragma unroll
    for (int i = 0; i < 4; i++) {
        int g = tid + 256 * i;
        int t = g >> 4, jg = g & 15;
        short8v vv = *(const short8v*)(QKVG + (size_t)(tok0 + t) * NPROJ + 1024 + h * 256 + 128 + jg * 8);
        #pragma unroll
        for (int e = 0; e < 8; e++)
            VT[sw8(jg * 8 + e, t)] = (unsigned short)vv[e];
    }
    __syncthreads();
    {
        f32x4 uacc[8];
        #pragma unroll
        for (int jt = 0; jt < 8; jt++) uacc[jt] = (f32x4){0.f, 0.f, 0.f, 0.f};
        #pragma unroll
        for (int ks = 0; ks < 2; ks++) {
            short8v at = *(const short8v*)(Tb + sw8(16 * wv + fr, 32 * ks + 8 * fq));
            #pragma unroll
            for (int jt = 0; jt < 8; jt++) {
                short8v bv = *(const short8v*)(VT + sw8(16 * jt + fr, 32 * ks + 8 * fq));
                uacc[jt] = __builtin_amdgcn_mfma_f32_16x16x32_bf16(at, bv, uacc[jt], 0, 0, 0);
            }
        }
        #pragma unroll
        for (int jt = 0; jt < 8; jt++)
            #pragma unroll
            for (int r = 0; r < 4; r++) {
                int t = 16 * wv + 4 * fq + r, j = 16 * jt + fr;
                Ubuf[cb * 16384 + (size_t)t * 256 + 128 + j] = f2bf(uacc[jt][r]);
            }
    }
}

// ---------------- MFMA chunk scan, 32x32x16, reg-resident A-operands ----------------
// grid (4 dv-slices, 8 bh), 256 threads (4 waves). State S[128][64] f32 in accumulators.
// LDS: ST[64][128] (16KB, XOR-16 swizzle), DT[64][64] (8KB, XOR-8). 2 barriers/chunk.
__global__ __launch_bounds__(256, 1) void scan_mfma(
    const us* __restrict__ QKVG, const us* __restrict__ Wbuf,
    const us* __restrict__ Ubuf, const us* __restrict__ Pbuf,
    const us* __restrict__ KTbuf, us* __restrict__ Ob)
{
    __shared__ us ST[8192];
    __shared__ us DT[4096];
    int tid = threadIdx.x;
    int wv = tid >> 6, ln = tid & 63;
    int l31 = ln & 31, hl = ln >> 5;
    int wt2 = wv >> 1, wj2 = wv & 1;
    int j0 = blockIdx.x * 64;
    int bh = blockIdx.y;
    int b = bh >> 2, h = bh & 3;

    // shifted-identity B fragments for 32x32x16 (k = 8*hl + e, n = l31)
    short8v id0, id1;
    #pragma unroll
    for (int e = 0; e < 8; e++) {
        id0[e] = (short)((8 * hl + e == l31) ? 0x3F80 : 0);
        id1[e] = (short)((8 * hl + e == l31 - 16) ? 0x3F80 : 0);
    }

    f32x16 sacc0, sacc1;
    #pragma unroll
    for (int i = 0; i < 16; i++) { sacc0[i] = 0.f; sacc1[i] = 0.f; }

    short8v Aw0[8], Aq0[8], Au0[2], Ap0[4], Ak0[8];
    short8v Aw1[8], Aq1[8], Au1[2], Ap1[4], Ak1[8];

    auto issue = [&](short8v (&Aw)[8], short8v (&Aq)[8], short8v (&Au)[2],
                     short8v (&Ap)[4], short8v (&Ak)[8], int cc) {
        size_t cb = (size_t)bh * NCHUNK + cc;
        const us* Wc = Wbuf + cb * 8192;
        const us* Uc = Ubuf + cb * 16384;
        const us* Pc = Pbuf + cb * 4096;
        const us* Kc = KTbuf + cb * 8192;
        const us* Qc = QKVG + (size_t)(b * SEQ + cc * 64) * NPROJ + h * 128;
        #pragma unroll
        for (int k8 = 0; k8 < 8; k8++) {
            Aw[k8] = *(const short8v*)(Wc + (32 * wt2 + l31) * 128 + 16 * k8 + 8 * hl);
            Aq[k8] = *(const short8v*)(Qc + (size_t)(32 * wt2 + l31) * NPROJ + 16 * k8 + 8 * hl);
        }
        #pragma unroll
        for (int jt = 0; jt < 2; jt++)
            Au[jt] = *(const short8v*)(Uc + (32 * wt2 + l31) * 256 + j0 + 32 * wj2 + 16 * jt + 8 * hl);
        #pragma unroll
        for (int k = 0; k < 4; k++)
            Ap[k] = *(const short8v*)(Pc + (32 * wt2 + l31) * 64 + 16 * k + 8 * hl);
        #pragma unroll
        for (int i = 0; i < 8; i++) {
            int dt2 = i >> 2, k = i & 3;
            Ak[i] = *(const short8v*)(Kc + (64 * wt2 + 32 * dt2 + l31) * 64 + 16 * k + 8 * hl);
        }
    };

    auto body = [&](short8v (&Aw)[8], short8v (&Aq)[8], short8v (&Au)[2],
                    short8v (&Ap)[4], short8v (&Ak)[8],
                    short8v (&Nw)[8], short8v (&Nq)[8], short8v (&Nu)[2],
                    short8v (&Np)[4], short8v (&Nk)[8], int c) {
        // phase A: dump state S -> ST[j][d] (bf16, swizzled)
        #pragma unroll
        for (int dt2 = 0; dt2 < 2; dt2++) {
            #pragma unroll
            for (int g = 0; g < 4; g++) {
                int d0 = 64 * wt2 + 32 * dt2 + 8 * g + 4 * hl;
                float v0 = dt2 ? sacc1[4 * g + 0] : sacc0[4 * g + 0];
                float v1 = dt2 ? sacc1[4 * g + 1] : sacc0[4 * g + 1];
                float v2 = dt2 ? sacc1[4 * g + 2] : sacc0[4 * g + 2];
                float v3 = dt2 ? sacc1[4 * g + 3] : sacc0[4 * g + 3];
                uint2 w;
                w.x = cvtpk(v0, v1);
                w.y = cvtpk(v2, v3);
                *(uint2*)&ST[swST(32 * wj2 + l31, d0)] = w;
            }
        }
        if (c < NCHUNK - 1) issue(Nw, Nq, Nu, Np, Nk, c + 1);
        bar_lgkm();

        // phase B: dacc = (-W)*S + U, oacc = Q*S
        f32x16 dacc, oacc;
        #pragma unroll
        for (int i = 0; i < 16; i++) { dacc[i] = 0.f; oacc[i] = 0.f; }
        #pragma unroll
        for (int k8 = 0; k8 < 8; k8++) {
            short8v bs = *(const short8v*)&ST[swST(32 * wj2 + l31, 16 * k8 + 8 * hl)];
            dacc = __builtin_amdgcn_mfma_f32_32x32x16_bf16(Aw[k8], bs, dacc, 0, 0, 0);
            oacc = __builtin_amdgcn_mfma_f32_32x32x16_bf16(Aq[k8], bs, oacc, 0, 0, 0);
        }
        dacc = __builtin_amdgcn_mfma_f32_32x32x16_bf16(Au[0], id0, dacc, 0, 0, 0);
        dacc = __builtin_amdgcn_mfma_f32_32x32x16_bf16(Au[1], id1, dacc, 0, 0, 0);
        #pragma unroll
        for (int i = 0; i < 16; i++) oacc[i] *= SCQ;
        // Delta -> DT[j][t] (transpose via C-layout: lane holds col j, regs span t)
        #pragma unroll
        for (int g = 0; g < 4; g++) {
            int tb = 32 * wt2 + 8 * g + 4 * hl;
            uint2 w;
            w.x = cvtpk(dacc[4 * g + 0], dacc[4 * g + 1]);
            w.y = cvtpk(dacc[4 * g + 2], dacc[4 * g + 3]);
            *(uint2*)&DT[swDT(32 * wj2 + l31, tb)] = w;
        }
        bar_lgkm();

        // phase C: oacc += P*Delta ; S += K^T*Delta ; store O
        short8v bd[4];
        #pragma unroll
        for (int k = 0; k < 4; k++)
            bd[k] = *(const short8v*)&DT[swDT(32 * wj2 + l31, 16 * k + 8 * hl)];
        #pragma unroll
        for (int k = 0; k < 4; k++) {
            oacc = __builtin_amdgcn_mfma_f32_32x32x16_bf16(Ap[k], bd[k], oacc, 0, 0, 0);
            sacc0 = __builtin_amdgcn_mfma_f32_32x32x16_bf16(Ak[k], bd[k], sacc0, 0, 0, 0);
            sacc1 = __builtin_amdgcn_mfma_f32_32x32x16_bf16(Ak[4 + k], bd[k], sacc1, 0, 0, 0);
        }
        int tok0 = b * SEQ + c * 64;
        us* ob = Ob + (size_t)tok0 * 1024 + h * 256 + j0 + 32 * wj2 + l31;
        #pragma unroll
        for (int g = 0; g < 4; g++) {
            int tb = 32 * wt2 + 8 * g + 4 * hl;
            unsigned int u0 = cvtpk(oacc[4 * g + 0], oacc[4 * g + 1]);
            unsigned int u1 = cvtpk(oacc[4 * g + 2], oacc[4 * g + 3]);
            ob[(size_t)(tb + 0) * 1024] = (us)u0;
            ob[(size_t)(tb + 1) * 1024] = (us)(u0 >> 16);
            ob[(size_t)(tb + 2) * 1024] = (us)u1;
            ob[(size_t)(tb + 3) * 1024] = (us)(u1 >> 16);
        }
    };

    issue(Aw0, Aq0, Au0, Ap0, Ak0, 0);
    for (int c = 0; c < NCHUNK; c += 2) {
        body(Aw0, Aq0, Au0, Ap0, Ak0, Aw1, Aq1, Au1, Ap1, Ak1, c);
        body(Aw1, Aq1, Au1, Ap1, Ak1, Aw0, Aq0, Au0, Ap0, Ak0, c + 1);
    }
}

// ---------------- RMSNorm + swish gate (wave per (tok,h), vectorized) ----------------
__global__ __launch_bounds__(256) void gate_norm(const us* __restrict__ Ob,
                                                 const us* __restrict__ QKVG,
                                                 const float* __restrict__ norm_w,
                                                 us* __restrict__ o2)
{
    int gid = blockIdx.x * 4 + (threadIdx.x >> 6);
    int ln = threadIdx.x & 63;
    int tok = gid >> 2, h = gid & 3;
    size_t base = (size_t)tok * 1024 + h * 256 + ln * 4;
    uint2 ov = *(const uint2*)&Ob[base];
    float o0 = bf2f((us)ov.x), o1 = bf2f((us)(ov.x >> 16));
    float o2v = bf2f((us)ov.y), o3 = bf2f((us)(ov.y >> 16));
    float ss = o0 * o0 + o1 * o1 + o2v * o2v + o3 * o3;
    #pragma unroll
    for (int off = 32; off; off >>= 1) ss += __shfl_xor(ss, off);
    float r = rsqrtf(ss * (1.0f / 256.0f) + 1e-5f);
    uint2 gv = *(const uint2*)&QKVG[(size_t)tok * NPROJ + 2048 + h * 256 + ln * 4];
    float g0 = bf2f((us)gv.x), g1 = bf2f((us)(gv.x >> 16));
    float g2 = bf2f((us)gv.y), g3 = bf2f((us)(gv.y >> 16));
    float4 nw = *(const float4*)&norm_w[ln * 4];
    float r0 = o0 * r * nw.x * (g0 / (1.f + __expf(-g0)));
    float r1 = o1 * r * nw.y * (g1 / (1.f + __expf(-g1)));
    float r2 = o2v * r * nw.z * (g2 / (1.f + __expf(-g2)));
    float r3 = o3 * r * nw.w * (g3 / (1.f + __expf(-g3)));
    uint2 w;
    w.x = cvtpk(r0, r1);
    w.y = cvtpk(r2, r3);
    *(uint2*)&o2[base] = w;
}

// ---------------- launch ----------------
extern "C" void kernel_launch(void* const* d_in, const int* in_sizes, int n_in,
                              void* d_out, int out_size, void* d_ws, size_t ws_size,
                              hipStream_t stream) {
    const float* x      = (const float*)d_in[0];
    const float* Wq     = (const float*)d_in[1];
    const float* Wk     = (const float*)d_in[2];
    const float* Wv     = (const float*)d_in[3];
    const float* Wb     = (const float*)d_in[4];
    const float* Wg     = (const float*)d_in[5];
    const float* Wo     = (const float*)d_in[6];
    const float* norm_w = (const float*)d_in[7];
    float* out = (float*)d_out;

    char* ws = (char*)d_ws;
    us*    xb   = (us*)(ws + 0);          // 16,777,216
    us*    KTbuf= (us*)(ws + 0);          // aliases xb (dead after gemm<0>)
    us*    WT   = (us*)(ws + 16777216);   //  6,291,456
    us*    WoT  = (us*)(ws + 23068672);   //  2,097,152
    us*    QKVG = (us*)(ws + 25165824);   // 50,331,648
    float* beta = (float*)(ws + 75497472);//    131,072
    us*    Wbuf = (us*)(ws + 75628544);   //  8,388,608
    us*    Ubuf = (us*)(ws + 84017152);   // 16,777,216
    us*    Pbuf = (us*)(ws + 100794368);  //  4,194,304
    us*    Ob   = (us*)(ws + 104988672);  // 16,777,216
    us*    o2   = (us*)(ws + 121765888);  // 16,777,216

    convert_x<<<(NTOK * DM / 4 + 255) / 256, 256, 0, stream>>>(x, xb, NTOK * DM / 4);
    transpose_w<<<dim3(8, 16), 256, 0, stream>>>(Wq, WT, DM, 512);
    transpose_w<<<dim3(8, 16), 256, 0, stream>>>(Wk, WT + (size_t)512 * DM, DM, 512);
    transpose_w<<<dim3(16, 16), 256, 0, stream>>>(Wv, WT + (size_t)1024 * DM, DM, 1024);
    transpose_w<<<dim3(16, 16), 256, 0, stream>>>(Wg, WT + (size_t)2048 * DM, DM, 1024);
    transpose_w<<<dim3(16, 16), 256, 0, stream>>>(Wo, WoT, DM, 1024);
    beta_kernel<<<NTOK / 16, 256, 0, stream>>>(x, Wb, beta);
    gemm_bt<0><<<dim3(64, 24), 256, 0, stream>>>(xb, WT, (void*)QKVG, NTOK, NPROJ, DM);
    chunk_pre<<<dim3(NCHUNK, 8), 256, 0, stream>>>(QKVG, beta, Wbuf, Ubuf, Pbuf, KTbuf);
    scan_mfma<<<dim3(4, 8), 256, 0, stream>>>(QKVG, Wbuf, Ubuf, Pbuf, KTbuf, Ob);
    gate_norm<<<NTOK, 256, 0, stream>>>(Ob, QKVG, norm_w, o2);
    gemm_bt<1><<<dim3(64, 8), 256, 0, stream>>>(o2, WoT, (void*)out, NTOK, DM, DM);
}

// Round 6
// 390.248 us; speedup vs baseline: 1.2247x; 1.2247x over previous
//
#include <hip/hip_runtime.h>
#include <hip/hip_bf16.h>
#include <stdint.h>
#include <stddef.h>

typedef __attribute__((ext_vector_type(8))) short short8v;   // 8 bf16 = 4 VGPR
typedef __attribute__((ext_vector_type(4))) float f32x4;
typedef unsigned short us;

__device__ __forceinline__ float bf2f(unsigned short u) {
    return __uint_as_float(((unsigned int)u) << 16);
}
__device__ __forceinline__ unsigned short f2bf(float f) {
    unsigned int x = __float_as_uint(f);
    x += 0x7fffu + ((x >> 16) & 1u);   // RNE
    return (unsigned short)(x >> 16);
}
__device__ __forceinline__ unsigned int cvtpk(float lo, float hi) {
    unsigned int r;
    asm("v_cvt_pk_bf16_f32 %0, %1, %2" : "=v"(r) : "v"(lo), "v"(hi));
    return r;
}

#define NTOK 8192
#define DM   1024
#define NPROJ 3072     // q512 | k512 | v1024 | g1024
#define SEQ  4096
#define NCHUNK 64
#define SCQ 0.08838834764831845f   // 128^-0.5

#define GLDS16(g, l) __builtin_amdgcn_global_load_lds( \
    (const __attribute__((address_space(1))) void*)(g), \
    (__attribute__((address_space(3))) void*)(l), 16, 0, 0)

__device__ __forceinline__ void bar_lgkm() {
    asm volatile("s_waitcnt lgkmcnt(0)" ::: "memory");
    __builtin_amdgcn_s_barrier();
    __builtin_amdgcn_sched_barrier(0);
}

// ---- swizzles (element offsets, 2B elems) ----
// chunk_pre-internal (unchanged):
__device__ __forceinline__ int sw16(int row, int k) {
    int u = k >> 3;
    int us_ = (u & 8) | ((u ^ row) & 7);
    return row * 128 + us_ * 8 + (k & 7);
}
__device__ __forceinline__ int sw8(int row, int k) {
    int u = k >> 3;
    int us_ = (u ^ row) & 7;
    return row * 64 + us_ * 8 + (k & 7);
}
// shared producer/consumer swizzles:
__device__ __forceinline__ int sw128(int row, int k) {   // [R][128] tile
    int u = k >> 3;
    return row * 128 + ((u ^ row) & 15) * 8 + (k & 7);
}
__device__ __forceinline__ int sw64(int row, int k) {    // [R][64] tile
    int u = k >> 3;
    return row * 64 + ((u ^ row) & 7) * 8 + (k & 7);
}
// Ubuf [t][256]: two 128-wide halves, hi unit-bit preserved (64-slice extractable)
__device__ __forceinline__ int swU(int t, int j) {
    int jj = j & 127, u = jj >> 3;
    int us_ = (u & 8) | ((u ^ t) & 7);
    return t * 256 + (j >> 7) * 128 + us_ * 8 + (jj & 7);
}
__device__ __forceinline__ int swU128(int t, int jj) {   // read within staged half
    int u = jj >> 3;
    int us_ = (u & 8) | ((u ^ t) & 7);
    return t * 128 + us_ * 8 + (jj & 7);
}
// S^T image [64][128], full 4-bit XOR
__device__ __forceinline__ int swST(int row, int k) {
    int u = k >> 3;
    return row * 128 + ((u ^ row) & 15) * 8 + (k & 7);
}

// ---------------- elementwise / conversion ----------------
__global__ void convert_x(const float* __restrict__ x, us* __restrict__ xb, int n4) {
    int i = blockIdx.x * 256 + threadIdx.x;
    if (i >= n4) return;
    float4 v = ((const float4*)x)[i];
    uint2 o;
    o.x = cvtpk(v.x, v.y);
    o.y = cvtpk(v.z, v.w);
    ((uint2*)xb)[i] = o;
}

__global__ __launch_bounds__(256) void transpose_w(const float* __restrict__ src,
                                                   us* __restrict__ dst, int K, int N) {
    __shared__ float tl[64][65];
    int k0 = blockIdx.y * 64, n0 = blockIdx.x * 64;
    int tid = threadIdx.x;
    int tr = tid >> 6, tc = tid & 63;
    #pragma unroll
    for (int i = 0; i < 16; i++) {
        int kk = 4 * i + tr;
        tl[kk][tc] = src[(size_t)(k0 + kk) * N + n0 + tc];
    }
    __syncthreads();
    int n = tid >> 2, seg = (tid & 3) * 16;
    short8v a, b;
    #pragma unroll
    for (int e = 0; e < 8; e++) {
        a[e] = (short)f2bf(tl[seg + e][n]);
        b[e] = (short)f2bf(tl[seg + 8 + e][n]);
    }
    us* d = dst + (size_t)(n0 + n) * K + k0 + seg;
    *(short8v*)d = a;
    *(short8v*)(d + 8) = b;
}

__global__ __launch_bounds__(256) void beta_kernel(const float* __restrict__ x,
                                                   const float* __restrict__ Wb,
                                                   float* __restrict__ beta) {
    __shared__ float part[16][16][4];
    int tl = threadIdx.x >> 4, sg = threadIdx.x & 15;
    int tok = blockIdx.x * 16 + tl;
    const float4* xr = (const float4*)(x + (size_t)tok * DM);
    const float4* wb = (const float4*)Wb;
    float s0 = 0.f, s1 = 0.f, s2 = 0.f, s3 = 0.f;
    #pragma unroll
    for (int it = 0; it < 16; it++) {
        int f = it * 16 + sg;
        float4 xv = xr[f];
        float4 w0 = wb[4 * f + 0], w1 = wb[4 * f + 1], w2 = wb[4 * f + 2], w3 = wb[4 * f + 3];
        s0 += xv.x * w0.x + xv.y * w1.x + xv.z * w2.x + xv.w * w3.x;
        s1 += xv.x * w0.y + xv.y * w1.y + xv.z * w2.y + xv.w * w3.y;
        s2 += xv.x * w0.z + xv.y * w1.z + xv.z * w2.z + xv.w * w3.z;
        s3 += xv.x * w0.w + xv.y * w1.w + xv.z * w2.w + xv.w * w3.w;
    }
    part[tl][sg][0] = s0; part[tl][sg][1] = s1; part[tl][sg][2] = s2; part[tl][sg][3] = s3;
    __syncthreads();
    if (threadIdx.x < 64) {
        int tl2 = threadIdx.x >> 2, h = threadIdx.x & 3;
        float s = 0.f;
        #pragma unroll
        for (int g = 0; g < 16; g++) s += part[tl2][g][h];
        beta[(size_t)(blockIdx.x * 16 + tl2) * 4 + h] = 1.f / (1.f + __expf(-s));
    }
}

// ---------------- bf16 MFMA GEMM (unchanged r5) ----------------
template<int OUT_F32>
__global__ __launch_bounds__(256) void gemm_bt(
    const us* __restrict__ A, const us* __restrict__ BT,
    void* __restrict__ C, int M, int N, int K)
{
    __shared__ us As[128][32];
    __shared__ us Bs[128][32];
    int tid = threadIdx.x;
    int wave = tid >> 6, lane = tid & 63;
    int wr = (wave >> 1) * 64, wc = (wave & 1) * 64;
    int fr = lane & 15, fq = lane >> 4;
    int nbx = gridDim.x, nwg = nbx * gridDim.y;
    int wg = blockIdx.y * nbx + blockIdx.x;
    int cpx = nwg >> 3;
    wg = (wg & 7) * cpx + (wg >> 3);
    int m0 = (wg % nbx) * 128, n0 = (wg / nbx) * 128;

    f32x4 acc[4][4];
    #pragma unroll
    for (int i = 0; i < 4; i++)
        #pragma unroll
        for (int j = 0; j < 4; j++) acc[i][j] = (f32x4){0.f, 0.f, 0.f, 0.f};

    int srow = (lane >> 2);
    int sce  = (lane & 3) * 8;

    for (int k0 = 0; k0 < K; k0 += 32) {
        #pragma unroll
        for (int i = 0; i < 2; i++) {
            int seg = wave * 2 + i;
            int row = seg * 16 + srow;
            GLDS16(&A[(size_t)(m0 + row) * K + k0 + sce], &As[0][0] + seg * 512);
            GLDS16(&BT[(size_t)(n0 + row) * K + k0 + sce], &Bs[0][0] + seg * 512);
        }
        __syncthreads();
        short8v a[4], b[4];
        #pragma unroll
        for (int i = 0; i < 4; i++) {
            a[i] = *(const short8v*)&As[wr + i * 16 + fr][fq * 8];
            b[i] = *(const short8v*)&Bs[wc + i * 16 + fr][fq * 8];
        }
        #pragma unroll
        for (int i = 0; i < 4; i++)
            #pragma unroll
            for (int j = 0; j < 4; j++)
                acc[i][j] = __builtin_amdgcn_mfma_f32_16x16x32_bf16(a[i], b[j], acc[i][j], 0, 0, 0);
        __syncthreads();
    }
    #pragma unroll
    for (int i = 0; i < 4; i++)
        #pragma unroll
        for (int j = 0; j < 4; j++)
            #pragma unroll
            for (int t = 0; t < 4; t++) {
                int row = m0 + wr + i * 16 + fq * 4 + t;
                int col = n0 + wc + j * 16 + fr;
                float val = acc[i][j][t];
                if (OUT_F32) ((float*)C)[(size_t)row * N + col] = val;
                else ((us*)C)[(size_t)row * N + col] = f2bf(val);
            }
}

// ---------------- per-chunk precompute (now writes PRE-SWIZZLED buffers) ----------------
// Wbuf [t][sw128 d] = -T'K ; Ubuf [t][swU j] = T'V ; Pbuf [t][sw64 s] = SC*tril(QK^T);
// KTbuf = raw sw64 image of K^T [d][t].
__global__ __launch_bounds__(256) void chunk_pre(
    const us* __restrict__ QKVG, const float* __restrict__ beta,
    us* __restrict__ Wbuf, us* __restrict__ Ubuf,
    us* __restrict__ Pbuf, us* __restrict__ KTbuf)
{
    __shared__ us Ks[8192];
    __shared__ us KTs[8192];
    __shared__ us VT[8192];
    __shared__ us Tb[4096];
    __shared__ float Af[64][64];
    __shared__ float betas[64];

    int c = blockIdx.x, bh = blockIdx.y;
    int b = bh >> 2, h = bh & 3;
    int tid = threadIdx.x;
    int wv = tid >> 6, ln = tid & 63;
    int fr = ln & 15, fq = ln >> 4;
    int tok0 = b * SEQ + c * 64;
    size_t cb = (size_t)bh * NCHUNK + c;

    #pragma unroll
    for (int r = 0; r < 4; r++) {
        int idx = tid + 256 * r;
        int t = idx >> 4, u = idx & 15;
        short8v kv = *(const short8v*)(QKVG + (size_t)(tok0 + t) * NPROJ + 512 + h * 128 + u * 8);
        *(short8v*)(Ks + sw16(t, u * 8)) = kv;
    }
    if (tid < 64) betas[tid] = beta[(size_t)(tok0 + tid) * 4 + h];
    __syncthreads();

    {   // L2-normalize K rows
        int t = tid >> 2, p = tid & 3;
        short8v v[4];
        float ss = 0.f;
        #pragma unroll
        for (int uu = 0; uu < 4; uu++) {
            v[uu] = *(const short8v*)(Ks + sw16(t, (p * 4 + uu) * 8));
            #pragma unroll
            for (int e = 0; e < 8; e++) {
                float f = bf2f((unsigned short)v[uu][e]);
                ss += f * f;
            }
        }
        ss += __shfl_xor(ss, 1);
        ss += __shfl_xor(ss, 2);
        float rn = rsqrtf(ss + 1e-12f);
        #pragma unroll
        for (int uu = 0; uu < 4; uu++) {
            short8v o;
            #pragma unroll
            for (int e = 0; e < 8; e++)
                o[e] = (short)f2bf(bf2f((unsigned short)v[uu][e]) * rn);
            *(short8v*)(Ks + sw16(t, (p * 4 + uu) * 8)) = o;
        }
    }
    __syncthreads();

    {   // A = strict_tril(beta_t K K^T)
        f32x4 aacc[4];
        #pragma unroll
        for (int jt = 0; jt < 4; jt++) aacc[jt] = (f32x4){0.f, 0.f, 0.f, 0.f};
        #pragma unroll
        for (int ks = 0; ks < 4; ks++) {
            short8v ak = *(const short8v*)(Ks + sw16(16 * wv + fr, 32 * ks + 8 * fq));
            #pragma unroll
            for (int jt = 0; jt < 4; jt++) {
                short8v bk = *(const short8v*)(Ks + sw16(16 * jt + fr, 32 * ks + 8 * fq));
                aacc[jt] = __builtin_amdgcn_mfma_f32_16x16x32_bf16(ak, bk, aacc[jt], 0, 0, 0);
            }
        }
        #pragma unroll
        for (int jt = 0; jt < 4; jt++)
            #pragma unroll
            for (int r = 0; r < 4; r++) {
                int t = 16 * wv + 4 * fq + r, s = 16 * jt + fr;
                if (s < t) Af[t][s] = betas[t] * aacc[jt][r];
            }
    }
    __syncthreads();

    if (wv == 0) {   // wave0: T = (I+A)^{-1}
        int cc = ln;
        for (int t = 1; t < 64; t++) {
            float aown = Af[t][cc];
            float acc = 0.f;
            for (int s = cc + 1; s < t; s++)
                acc += Af[t][s] * Af[s][cc];
            if (cc < t) Af[t][cc] = -aown - acc;
        }
    } else {         // waves 1-3: K^T, V^T(half0) scatters
        int q = tid - 64;
        for (int g = q; g < 1024; g += 192) {
            int t = g >> 4, u = g & 15;
            short8v kv = *(const short8v*)(Ks + sw16(t, u * 8));
            #pragma unroll
            for (int e = 0; e < 8; e++)
                KTs[sw8(u * 8 + e, t)] = (unsigned short)kv[e];
        }
        for (int g = q; g < 1024; g += 192) {
            int t = g >> 4, jg = g & 15;
            short8v vv = *(const short8v*)(QKVG + (size_t)(tok0 + t) * NPROJ + 1024 + h * 256 + jg * 8);
            #pragma unroll
            for (int e = 0; e < 8; e++)
                VT[sw8(jg * 8 + e, t)] = (unsigned short)vv[e];
        }
    }
    __syncthreads();

    {   // P = SC*tril(QK^T), Tb, KTbuf image copy
        f32x4 pacc[4];
        #pragma unroll
        for (int jt = 0; jt < 4; jt++) pacc[jt] = (f32x4){0.f, 0.f, 0.f, 0.f};
        #pragma unroll
        for (int ks = 0; ks < 4; ks++) {
            short8v aq = *(const short8v*)(QKVG + (size_t)(tok0 + 16 * wv + fr) * NPROJ + h * 128 + ks * 32 + fq * 8);
            #pragma unroll
            for (int jt = 0; jt < 4; jt++) {
                short8v bk = *(const short8v*)(Ks + sw16(16 * jt + fr, 32 * ks + 8 * fq));
                pacc[jt] = __builtin_amdgcn_mfma_f32_16x16x32_bf16(aq, bk, pacc[jt], 0, 0, 0);
            }
        }
        #pragma unroll
        for (int jt = 0; jt < 4; jt++)
            #pragma unroll
            for (int r = 0; r < 4; r++) {
                int t = 16 * wv + 4 * fq + r, s = 16 * jt + fr;
                float val = (s <= t) ? pacc[jt][r] * SCQ : 0.f;
                Pbuf[cb * 4096 + sw64(t, s)] = f2bf(val);
            }
        #pragma unroll
        for (int i = 0; i < 16; i++) {
            int idx = tid + 256 * i;
            int t = idx >> 6, s = idx & 63;
            float tv = (s < t) ? Af[t][s] : (s == t ? 1.f : 0.f);
            Tb[sw8(t, s)] = f2bf(tv * betas[s]);
        }
        #pragma unroll
        for (int i = 0; i < 4; i++) {
            int idx = tid + 256 * i;   // raw image copy (already sw64)
            *(short8v*)(KTbuf + cb * 8192 + (size_t)idx * 8) =
                *(const short8v*)(KTs + (size_t)idx * 8);
        }
    }
    __syncthreads();

    {   // W = -(T'K), U half0
        f32x4 wacc[8], uacc[8];
        #pragma unroll
        for (int jt = 0; jt < 8; jt++) {
            wacc[jt] = (f32x4){0.f, 0.f, 0.f, 0.f};
            uacc[jt] = (f32x4){0.f, 0.f, 0.f, 0.f};
        }
        #pragma unroll
        for (int ks = 0; ks < 2; ks++) {
            short8v at = *(const short8v*)(Tb + sw8(16 * wv + fr, 32 * ks + 8 * fq));
            #pragma unroll
            for (int jt = 0; jt < 8; jt++) {
                short8v bk = *(const short8v*)(KTs + sw8(16 * jt + fr, 32 * ks + 8 * fq));
                wacc[jt] = __builtin_amdgcn_mfma_f32_16x16x32_bf16(at, bk, wacc[jt], 0, 0, 0);
                short8v bv = *(const short8v*)(VT + sw8(16 * jt + fr, 32 * ks + 8 * fq));
                uacc[jt] = __builtin_amdgcn_mfma_f32_16x16x32_bf16(at, bv, uacc[jt], 0, 0, 0);
            }
        }
        #pragma unroll
        for (int jt = 0; jt < 8; jt++)
            #pragma unroll
            for (int r = 0; r < 4; r++) {
                int t = 16 * wv + 4 * fq + r, d = 16 * jt + fr;
                Wbuf[cb * 8192 + sw128(t, d)] = f2bf(-wacc[jt][r]);
                Ubuf[cb * 16384 + swU(t, d)] = f2bf(uacc[jt][r]);
            }
    }
    __syncthreads();

    #pragma unroll
    for (int i = 0; i < 4; i++) {   // restage V^T half1
        int g = tid + 256 * i;
        int t = g >> 4, jg = g & 15;
        short8v vv = *(const short8v*)(QKVG + (size_t)(tok0 + t) * NPROJ + 1024 + h * 256 + 128 + jg * 8);
        #pragma unroll
        for (int e = 0; e < 8; e++)
            VT[sw8(jg * 8 + e, t)] = (unsigned short)vv[e];
    }
    __syncthreads();
    {
        f32x4 uacc[8];
        #pragma unroll
        for (int jt = 0; jt < 8; jt++) uacc[jt] = (f32x4){0.f, 0.f, 0.f, 0.f};
        #pragma unroll
        for (int ks = 0; ks < 2; ks++) {
            short8v at = *(const short8v*)(Tb + sw8(16 * wv + fr, 32 * ks + 8 * fq));
            #pragma unroll
            for (int jt = 0; jt < 8; jt++) {
                short8v bv = *(const short8v*)(VT + sw8(16 * jt + fr, 32 * ks + 8 * fq));
                uacc[jt] = __builtin_amdgcn_mfma_f32_16x16x32_bf16(at, bv, uacc[jt], 0, 0, 0);
            }
        }
        #pragma unroll
        for (int jt = 0; jt < 8; jt++)
            #pragma unroll
            for (int r = 0; r < 4; r++) {
                int t = 16 * wv + 4 * fq + r, j = 16 * jt + fr;
                Ubuf[cb * 16384 + swU(t, 128 + j)] = f2bf(uacc[jt][r]);
            }
    }
}

// ---------------- serial scan: Delta = U - W*S ; S += K^T*Delta ; dump S-hat ----------------
// grid (4 dv-slices, 8 bh), 256 thr. LDS: dbuf{W 8192 | KT 8192 | U 4096} x2 + ST 8192 + DT 4096
#define SC_W 0
#define SC_KT 8192
#define SC_U 16384
#define SC_BUFSZ 20480
#define SC_ST 40960
#define SC_DT 49152
// total 53248 elems = 106496 B

__global__ __launch_bounds__(256, 1) void scan_mfma(
    const us* __restrict__ Wbuf, const us* __restrict__ Ubuf,
    const us* __restrict__ KTbuf, us* __restrict__ Sbuf)
{
    extern __shared__ us lds[];
    int tid = threadIdx.x;
    int wv = tid >> 6, ln = tid & 63;
    int fr = ln & 15, fq = ln >> 4;
    int sl = blockIdx.x;
    int j0 = sl * 64;
    int bh = blockIdx.y;

    short8v id0, id1;
    #pragma unroll
    for (int e = 0; e < 8; e++) {
        id0[e] = (short)((8 * fq + e == fr) ? 0x3F80 : 0);
        id1[e] = (short)((8 * fq + e == fr + 16) ? 0x3F80 : 0);
    }

    f32x4 sacc[2][4];
    #pragma unroll
    for (int i = 0; i < 2; i++)
        #pragma unroll
        for (int j = 0; j < 4; j++) sacc[i][j] = (f32x4){0.f, 0.f, 0.f, 0.f};

    auto issue = [&](int c1) {
        size_t cb = (size_t)bh * NCHUNK + c1;
        us* dst = lds + (c1 & 1) * SC_BUFSZ;
        #pragma unroll
        for (int i = 0; i < 4; i++) {
            int q = (i * 4 + wv) * 512 + ln * 8;
            GLDS16(Wbuf + cb * 8192 + q, dst + SC_W + (i * 4 + wv) * 512);
            GLDS16(KTbuf + cb * 8192 + q, dst + SC_KT + (i * 4 + wv) * 512);
        }
        #pragma unroll
        for (int i = 0; i < 2; i++) {
            int q = (i * 4 + wv) * 512 + ln * 8;
            int t = q >> 6, r = q & 63;
            GLDS16(Ubuf + cb * 16384 + t * 256 + j0 + r, dst + SC_U + (i * 4 + wv) * 512);
        }
    };

    issue(0);
    asm volatile("s_waitcnt vmcnt(0)" ::: "memory");
    __syncthreads();

    for (int c = 0; c < NCHUNK; c++) {
        const us* bw = lds + (c & 1) * SC_BUFSZ;
        if (c + 1 < NCHUNK) issue(c + 1);
        // phase A: dump S -> ST (bf16, swizzled)
        #pragma unroll
        for (int dtt = 0; dtt < 2; dtt++)
            #pragma unroll
            for (int jt = 0; jt < 4; jt++) {
                int d0 = 32 * wv + 16 * dtt + 4 * fq;
                int j = 16 * jt + fr;
                f32x4 v = sacc[dtt][jt];
                uint2 w;
                w.x = cvtpk(v[0], v[1]);
                w.y = cvtpk(v[2], v[3]);
                *(uint2*)&lds[SC_ST + swST(j, d0)] = w;
            }
        bar_lgkm();

        // phase B: ST image -> Sbuf (coalesced); dacc = (-W)*S + U
        size_t sb = ((size_t)(bh * NCHUNK + c) * 4 + sl) * 8192;
        #pragma unroll
        for (int i = 0; i < 4; i++) {
            short8v v = *(const short8v*)&lds[SC_ST + tid * 8 + i * 2048];
            *(short8v*)(Sbuf + sb + tid * 8 + i * 2048) = v;
        }
        f32x4 dacc[4];
        #pragma unroll
        for (int jt = 0; jt < 4; jt++) dacc[jt] = (f32x4){0.f, 0.f, 0.f, 0.f};
        #pragma unroll
        for (int ks = 0; ks < 4; ks++) {
            short8v aw = *(const short8v*)&bw[SC_W + sw128(16 * wv + fr, 32 * ks + 8 * fq)];
            #pragma unroll
            for (int jt = 0; jt < 4; jt++) {
                short8v bs = *(const short8v*)&lds[SC_ST + swST(16 * jt + fr, 32 * ks + 8 * fq)];
                dacc[jt] = __builtin_amdgcn_mfma_f32_16x16x32_bf16(aw, bs, dacc[jt], 0, 0, 0);
            }
        }
        #pragma unroll
        for (int ju = 0; ju < 2; ju++) {
            short8v au = *(const short8v*)&bw[SC_U + sw64(16 * wv + fr, 32 * ju + 8 * fq)];
            dacc[2 * ju + 0] = __builtin_amdgcn_mfma_f32_16x16x32_bf16(au, id0, dacc[2 * ju + 0], 0, 0, 0);
            dacc[2 * ju + 1] = __builtin_amdgcn_mfma_f32_16x16x32_bf16(au, id1, dacc[2 * ju + 1], 0, 0, 0);
        }
        // Delta -> DT[j][t]
        #pragma unroll
        for (int jt = 0; jt < 4; jt++) {
            int j = 16 * jt + fr;
            int t0 = 16 * wv + 4 * fq;
            uint2 w;
            w.x = cvtpk(dacc[jt][0], dacc[jt][1]);
            w.y = cvtpk(dacc[jt][2], dacc[jt][3]);
            *(uint2*)&lds[SC_DT + sw64(j, t0)] = w;
        }
        bar_lgkm();

        // phase C: S += K^T * Delta
        #pragma unroll
        for (int ks = 0; ks < 2; ks++) {
            short8v ak0 = *(const short8v*)&bw[SC_KT + sw64(32 * wv + fr, 32 * ks + 8 * fq)];
            short8v ak1 = *(const short8v*)&bw[SC_KT + sw64(32 * wv + 16 + fr, 32 * ks + 8 * fq)];
            #pragma unroll
            for (int jt = 0; jt < 4; jt++) {
                short8v bd = *(const short8v*)&lds[SC_DT + sw64(16 * jt + fr, 32 * ks + 8 * fq)];
                sacc[0][jt] = __builtin_amdgcn_mfma_f32_16x16x32_bf16(ak0, bd, sacc[0][jt], 0, 0, 0);
                sacc[1][jt] = __builtin_amdgcn_mfma_f32_16x16x32_bf16(ak1, bd, sacc[1][jt], 0, 0, 0);
            }
        }
        asm volatile("s_waitcnt vmcnt(0)" ::: "memory");   // next buf landed
        bar_lgkm();
    }
}

// ---------------- parallel output: O = SCQ*Q*S-hat + P*(U - W*S-hat) ----------------
// grid (64 chunks, 16 = bh*2 + jhalf), 256 thr.
#define K2_W 0
#define K2_P 8192
#define K2_U 12288
#define K2_S 20480
#define K2_Q 36864
#define K2_DT 45056
// total 53248 elems = 106496 B

__global__ __launch_bounds__(256, 1) void out_k(
    const us* __restrict__ QKVG, const us* __restrict__ Wbuf,
    const us* __restrict__ Ubuf, const us* __restrict__ Pbuf,
    const us* __restrict__ Sbuf, us* __restrict__ Ob)
{
    extern __shared__ us lds[];
    int tid = threadIdx.x;
    int wv = tid >> 6, ln = tid & 63;
    int fr = ln & 15, fq = ln >> 4;
    int c = blockIdx.x;
    int bh = blockIdx.y >> 1, jh = blockIdx.y & 1;
    int b = bh >> 2, h = bh & 3;
    int tok0 = b * SEQ + c * 64;
    size_t cb = (size_t)bh * NCHUNK + c;

    short8v id0, id1;
    #pragma unroll
    for (int e = 0; e < 8; e++) {
        id0[e] = (short)((8 * fq + e == fr) ? 0x3F80 : 0);
        id1[e] = (short)((8 * fq + e == fr + 16) ? 0x3F80 : 0);
    }

    // stage W, P, U-half, S (2 images)
    #pragma unroll
    for (int i = 0; i < 4; i++) {
        int q = (i * 4 + wv) * 512 + ln * 8;
        GLDS16(Wbuf + cb * 8192 + q, lds + K2_W + (i * 4 + wv) * 512);
    }
    #pragma unroll
    for (int i = 0; i < 2; i++) {
        int q = (i * 4 + wv) * 512 + ln * 8;
        GLDS16(Pbuf + cb * 4096 + q, lds + K2_P + (i * 4 + wv) * 512);
    }
    #pragma unroll
    for (int i = 0; i < 4; i++) {
        int q = (i * 4 + wv) * 512 + ln * 8;
        int t = q >> 7, r = q & 127;
        GLDS16(Ubuf + cb * 16384 + t * 256 + jh * 128 + r, lds + K2_U + (i * 4 + wv) * 512);
    }
    size_t sbase = ((size_t)cb * 4 + jh * 2) * 8192;
    #pragma unroll
    for (int i = 0; i < 8; i++) {
        int q = (i * 4 + wv) * 512 + ln * 8;
        GLDS16(Sbuf + sbase + q, lds + K2_S + (i * 4 + wv) * 512);
    }
    // Q reg-stage with swizzled commit
    short8v qv[4];
    #pragma unroll
    for (int i = 0; i < 4; i++) {
        int idx = tid + 256 * i;
        int t = idx >> 4, u = idx & 15;
        qv[i] = *(const short8v*)(QKVG + (size_t)(tok0 + t) * NPROJ + h * 128 + u * 8);
    }
    #pragma unroll
    for (int i = 0; i < 4; i++) {
        int idx = tid + 256 * i;
        int t = idx >> 4, u = idx & 15;
        *(short8v*)&lds[K2_Q + sw128(t, u * 8)] = qv[i];
    }
    __syncthreads();

    // phase B: dacc = (-W)*S + U ; oacc = Q*S
    f32x4 dacc[8], oacc[8];
    #pragma unroll
    for (int jt = 0; jt < 8; jt++) {
        dacc[jt] = (f32x4){0.f, 0.f, 0.f, 0.f};
        oacc[jt] = (f32x4){0.f, 0.f, 0.f, 0.f};
    }
    #pragma unroll
    for (int ks = 0; ks < 4; ks++) {
        short8v aw = *(const short8v*)&lds[K2_W + sw128(16 * wv + fr, 32 * ks + 8 * fq)];
        short8v aq = *(const short8v*)&lds[K2_Q + sw128(16 * wv + fr, 32 * ks + 8 * fq)];
        #pragma unroll
        for (int jt = 0; jt < 8; jt++) {
            int j = 16 * jt + fr;
            short8v bs = *(const short8v*)&lds[K2_S + (j >> 6) * 8192 + swST(j & 63, 32 * ks + 8 * fq)];
            dacc[jt] = __builtin_amdgcn_mfma_f32_16x16x32_bf16(aw, bs, dacc[jt], 0, 0, 0);
            oacc[jt] = __builtin_amdgcn_mfma_f32_16x16x32_bf16(aq, bs, oacc[jt], 0, 0, 0);
        }
    }
    #pragma unroll
    for (int ju = 0; ju < 4; ju++) {
        short8v au = *(const short8v*)&lds[K2_U + swU128(16 * wv + fr, 32 * ju + 8 * fq)];
        dacc[2 * ju + 0] = __builtin_amdgcn_mfma_f32_16x16x32_bf16(au, id0, dacc[2 * ju + 0], 0, 0, 0);
        dacc[2 * ju + 1] = __builtin_amdgcn_mfma_f32_16x16x32_bf16(au, id1, dacc[2 * ju + 1], 0, 0, 0);
    }
    #pragma unroll
    for (int jt = 0; jt < 8; jt++)
        #pragma unroll
        for (int r = 0; r < 4; r++) oacc[jt][r] *= SCQ;
    // Delta -> DT[j][t]
    #pragma unroll
    for (int jt = 0; jt < 8; jt++) {
        int j = 16 * jt + fr;
        int t0 = 16 * wv + 4 * fq;
        uint2 w;
        w.x = cvtpk(dacc[jt][0], dacc[jt][1]);
        w.y = cvtpk(dacc[jt][2], dacc[jt][3]);
        *(uint2*)&lds[K2_DT + sw64(j, t0)] = w;
    }
    bar_lgkm();

    // phase C: oacc += P * Delta ; store O
    #pragma unroll
    for (int ks = 0; ks < 2; ks++) {
        short8v ap = *(const short8v*)&lds[K2_P + sw64(16 * wv + fr, 32 * ks + 8 * fq)];
        #pragma unroll
        for (int jt = 0; jt < 8; jt++) {
            short8v bd = *(const short8v*)&lds[K2_DT + sw64(16 * jt + fr, 32 * ks + 8 * fq)];
            oacc[jt] = __builtin_amdgcn_mfma_f32_16x16x32_bf16(ap, bd, oacc[jt], 0, 0, 0);
        }
    }
    us* ob = Ob + (size_t)tok0 * 1024 + h * 256 + jh * 128;
    #pragma unroll
    for (int jt = 0; jt < 8; jt++)
        #pragma unroll
        for (int r = 0; r < 4; r++) {
            int t = 16 * wv + 4 * fq + r;
            ob[(size_t)t * 1024 + 16 * jt + fr] = f2bf(oacc[jt][r]);
        }
}

// ---------------- RMSNorm + swish gate ----------------
__global__ __launch_bounds__(256) void gate_norm(const us* __restrict__ Ob,
                                                 const us* __restrict__ QKVG,
                                                 const float* __restrict__ norm_w,
                                                 us* __restrict__ o2)
{
    int gid = blockIdx.x * 4 + (threadIdx.x >> 6);
    int ln = threadIdx.x & 63;
    int tok = gid >> 2, h = gid & 3;
    size_t base = (size_t)tok * 1024 + h * 256 + ln * 4;
    uint2 ov = *(const uint2*)&Ob[base];
    float o0 = bf2f((us)ov.x), o1 = bf2f((us)(ov.x >> 16));
    float o2v = bf2f((us)ov.y), o3 = bf2f((us)(ov.y >> 16));
    float ss = o0 * o0 + o1 * o1 + o2v * o2v + o3 * o3;
    #pragma unroll
    for (int off = 32; off; off >>= 1) ss += __shfl_xor(ss, off);
    float r = rsqrtf(ss * (1.0f / 256.0f) + 1e-5f);
    uint2 gv = *(const uint2*)&QKVG[(size_t)tok * NPROJ + 2048 + h * 256 + ln * 4];
    float g0 = bf2f((us)gv.x), g1 = bf2f((us)(gv.x >> 16));
    float g2 = bf2f((us)gv.y), g3 = bf2f((us)(gv.y >> 16));
    float4 nw = *(const float4*)&norm_w[ln * 4];
    float r0 = o0 * r * nw.x * (g0 / (1.f + __expf(-g0)));
    float r1 = o1 * r * nw.y * (g1 / (1.f + __expf(-g1)));
    float r2 = o2v * r * nw.z * (g2 / (1.f + __expf(-g2)));
    float r3 = o3 * r * nw.w * (g3 / (1.f + __expf(-g3)));
    uint2 w;
    w.x = cvtpk(r0, r1);
    w.y = cvtpk(r2, r3);
    *(uint2*)&o2[base] = w;
}

// ---------------- launch ----------------
extern "C" void kernel_launch(void* const* d_in, const int* in_sizes, int n_in,
                              void* d_out, int out_size, void* d_ws, size_t ws_size,
                              hipStream_t stream) {
    const float* x      = (const float*)d_in[0];
    const float* Wq     = (const float*)d_in[1];
    const float* Wk     = (const float*)d_in[2];
    const float* Wv     = (const float*)d_in[3];
    const float* Wb     = (const float*)d_in[4];
    const float* Wg     = (const float*)d_in[5];
    const float* Wo     = (const float*)d_in[6];
    const float* norm_w = (const float*)d_in[7];
    float* out = (float*)d_out;

    char* ws = (char*)d_ws;
    // lifetimes: xb,WT dead after gemm0 -> Sbuf aliases; KTbuf dead after scan -> Ob aliases;
    // Ubuf dead after out_k -> o2 aliases.
    us*    xb   = (us*)(ws + 0);            // 16 MB
    us*    WT   = (us*)(ws + 16777216);     //  6 MB
    us*    Sbuf = (us*)(ws + 0);            // 32 MB (alias xb+WT)
    us*    KTbuf= (us*)(ws + 33554432);     //  8 MB
    us*    Ob   = (us*)(ws + 33554432);     // 16 MB (alias KTbuf)
    us*    QKVG = (us*)(ws + 50331648);     // 48 MB
    float* beta = (float*)(ws + 100663296); // 128 KB
    us*    Wbuf = (us*)(ws + 100794368);    //  8 MB
    us*    Ubuf = (us*)(ws + 109182976);    // 16 MB
    us*    o2   = (us*)(ws + 109182976);    // (alias Ubuf)
    us*    Pbuf = (us*)(ws + 125960192);    //  4 MB
    us*    WoT  = (us*)(ws + 130154496);    //  2 MB  (end ~126.1 MB)

    (void)hipFuncSetAttribute((const void*)scan_mfma,
                              hipFuncAttributeMaxDynamicSharedMemorySize, 106496);
    (void)hipFuncSetAttribute((const void*)out_k,
                              hipFuncAttributeMaxDynamicSharedMemorySize, 106496);

    convert_x<<<(NTOK * DM / 4 + 255) / 256, 256, 0, stream>>>(x, xb, NTOK * DM / 4);
    transpose_w<<<dim3(8, 16), 256, 0, stream>>>(Wq, WT, DM, 512);
    transpose_w<<<dim3(8, 16), 256, 0, stream>>>(Wk, WT + (size_t)512 * DM, DM, 512);
    transpose_w<<<dim3(16, 16), 256, 0, stream>>>(Wv, WT + (size_t)1024 * DM, DM, 1024);
    transpose_w<<<dim3(16, 16), 256, 0, stream>>>(Wg, WT + (size_t)2048 * DM, DM, 1024);
    transpose_w<<<dim3(16, 16), 256, 0, stream>>>(Wo, WoT, DM, 1024);
    beta_kernel<<<NTOK / 16, 256, 0, stream>>>(x, Wb, beta);
    gemm_bt<0><<<dim3(64, 24), 256, 0, stream>>>(xb, WT, (void*)QKVG, NTOK, NPROJ, DM);
    chunk_pre<<<dim3(NCHUNK, 8), 256, 0, stream>>>(QKVG, beta, Wbuf, Ubuf, Pbuf, KTbuf);
    scan_mfma<<<dim3(4, 8), 256, 106496, stream>>>(Wbuf, Ubuf, KTbuf, Sbuf);
    out_k<<<dim3(NCHUNK, 16), 256, 106496, stream>>>(QKVG, Wbuf, Ubuf, Pbuf, Sbuf, Ob);
    gate_norm<<<NTOK, 256, 0, stream>>>(Ob, QKVG, norm_w, o2);
    gemm_bt<1><<<dim3(64, 8), 256, 0, stream>>>(o2, WoT, (void*)out, NTOK, DM, DM);
}

// Round 7
// 372.810 us; speedup vs baseline: 1.2820x; 1.0468x over previous
//
#include <hip/hip_runtime.h>
#include <hip/hip_bf16.h>
#include <stdint.h>
#include <stddef.h>

typedef __attribute__((ext_vector_type(8))) short short8v;   // 8 bf16 = 4 VGPR
typedef __attribute__((ext_vector_type(4))) float f32x4;
typedef unsigned short us;

__device__ __forceinline__ float bf2f(unsigned short u) {
    return __uint_as_float(((unsigned int)u) << 16);
}
__device__ __forceinline__ unsigned short f2bf(float f) {
    unsigned int x = __float_as_uint(f);
    x += 0x7fffu + ((x >> 16) & 1u);   // RNE
    return (unsigned short)(x >> 16);
}
__device__ __forceinline__ unsigned int cvtpk(float lo, float hi) {
    unsigned int r;
    asm("v_cvt_pk_bf16_f32 %0, %1, %2" : "=v"(r) : "v"(lo), "v"(hi));
    return r;
}

#define NTOK 8192
#define DM   1024
#define NPROJ 3072     // q512 | k512 | v1024 | g1024
#define SEQ  4096
#define NCHUNK 64
#define SCQ 0.08838834764831845f   // 128^-0.5

#define GLDS16(g, l) __builtin_amdgcn_global_load_lds( \
    (const __attribute__((address_space(1))) void*)(g), \
    (__attribute__((address_space(3))) void*)(l), 16, 0, 0)

__device__ __forceinline__ void bar_lgkm() {
    asm volatile("s_waitcnt lgkmcnt(0)" ::: "memory");
    __builtin_amdgcn_s_barrier();
    __builtin_amdgcn_sched_barrier(0);
}

// ---- swizzles (element offsets, 2B elems) ----
__device__ __forceinline__ int sw16(int row, int k) {
    int u = k >> 3;
    int us_ = (u & 8) | ((u ^ row) & 7);
    return row * 128 + us_ * 8 + (k & 7);
}
__device__ __forceinline__ int sw8(int row, int k) {
    int u = k >> 3;
    int us_ = (u ^ row) & 7;
    return row * 64 + us_ * 8 + (k & 7);
}
__device__ __forceinline__ int sw128(int row, int k) {   // [R][128] tile
    int u = k >> 3;
    return row * 128 + ((u ^ row) & 15) * 8 + (k & 7);
}
__device__ __forceinline__ int sw64(int row, int k) {    // [R][64] tile
    int u = k >> 3;
    return row * 64 + ((u ^ row) & 7) * 8 + (k & 7);
}
__device__ __forceinline__ int swU(int t, int j) {       // Ubuf [t][256]
    int jj = j & 127, u = jj >> 3;
    int us_ = (u & 8) | ((u ^ t) & 7);
    return t * 256 + (j >> 7) * 128 + us_ * 8 + (jj & 7);
}
__device__ __forceinline__ int swU128(int t, int jj) {
    int u = jj >> 3;
    int us_ = (u & 8) | ((u ^ t) & 7);
    return t * 128 + us_ * 8 + (jj & 7);
}
__device__ __forceinline__ int swST(int row, int k) {    // S image [j][128d]
    int u = k >> 3;
    return row * 128 + ((u ^ row) & 15) * 8 + (k & 7);
}

// ---------------- elementwise / conversion ----------------
__global__ void convert_x(const float* __restrict__ x, us* __restrict__ xb, int n4) {
    int i = blockIdx.x * 256 + threadIdx.x;
    if (i >= n4) return;
    float4 v = ((const float4*)x)[i];
    uint2 o;
    o.x = cvtpk(v.x, v.y);
    o.y = cvtpk(v.z, v.w);
    ((uint2*)xb)[i] = o;
}

__global__ __launch_bounds__(256) void transpose_w(const float* __restrict__ src,
                                                   us* __restrict__ dst, int K, int N) {
    __shared__ float tl[64][65];
    int k0 = blockIdx.y * 64, n0 = blockIdx.x * 64;
    int tid = threadIdx.x;
    int tr = tid >> 6, tc = tid & 63;
    #pragma unroll
    for (int i = 0; i < 16; i++) {
        int kk = 4 * i + tr;
        tl[kk][tc] = src[(size_t)(k0 + kk) * N + n0 + tc];
    }
    __syncthreads();
    int n = tid >> 2, seg = (tid & 3) * 16;
    short8v a, b;
    #pragma unroll
    for (int e = 0; e < 8; e++) {
        a[e] = (short)f2bf(tl[seg + e][n]);
        b[e] = (short)f2bf(tl[seg + 8 + e][n]);
    }
    us* d = dst + (size_t)(n0 + n) * K + k0 + seg;
    *(short8v*)d = a;
    *(short8v*)(d + 8) = b;
}

__global__ __launch_bounds__(256) void beta_kernel(const float* __restrict__ x,
                                                   const float* __restrict__ Wb,
                                                   float* __restrict__ beta) {
    __shared__ float part[16][16][4];
    int tl = threadIdx.x >> 4, sg = threadIdx.x & 15;
    int tok = blockIdx.x * 16 + tl;
    const float4* xr = (const float4*)(x + (size_t)tok * DM);
    const float4* wb = (const float4*)Wb;
    float s0 = 0.f, s1 = 0.f, s2 = 0.f, s3 = 0.f;
    #pragma unroll
    for (int it = 0; it < 16; it++) {
        int f = it * 16 + sg;
        float4 xv = xr[f];
        float4 w0 = wb[4 * f + 0], w1 = wb[4 * f + 1], w2 = wb[4 * f + 2], w3 = wb[4 * f + 3];
        s0 += xv.x * w0.x + xv.y * w1.x + xv.z * w2.x + xv.w * w3.x;
        s1 += xv.x * w0.y + xv.y * w1.y + xv.z * w2.y + xv.w * w3.y;
        s2 += xv.x * w0.z + xv.y * w1.z + xv.z * w2.z + xv.w * w3.z;
        s3 += xv.x * w0.w + xv.y * w1.w + xv.z * w2.w + xv.w * w3.w;
    }
    part[tl][sg][0] = s0; part[tl][sg][1] = s1; part[tl][sg][2] = s2; part[tl][sg][3] = s3;
    __syncthreads();
    if (threadIdx.x < 64) {
        int tl2 = threadIdx.x >> 2, h = threadIdx.x & 3;
        float s = 0.f;
        #pragma unroll
        for (int g = 0; g < 16; g++) s += part[tl2][g][h];
        beta[(size_t)(blockIdx.x * 16 + tl2) * 4 + h] = 1.f / (1.f + __expf(-s));
    }
}

// ---------------- bf16 MFMA GEMM ----------------
template<int OUT_F32>
__global__ __launch_bounds__(256) void gemm_bt(
    const us* __restrict__ A, const us* __restrict__ BT,
    void* __restrict__ C, int M, int N, int K)
{
    __shared__ us As[128][32];
    __shared__ us Bs[128][32];
    int tid = threadIdx.x;
    int wave = tid >> 6, lane = tid & 63;
    int wr = (wave >> 1) * 64, wc = (wave & 1) * 64;
    int fr = lane & 15, fq = lane >> 4;
    int nbx = gridDim.x, nwg = nbx * gridDim.y;
    int wg = blockIdx.y * nbx + blockIdx.x;
    int cpx = nwg >> 3;
    wg = (wg & 7) * cpx + (wg >> 3);
    int m0 = (wg % nbx) * 128, n0 = (wg / nbx) * 128;

    f32x4 acc[4][4];
    #pragma unroll
    for (int i = 0; i < 4; i++)
        #pragma unroll
        for (int j = 0; j < 4; j++) acc[i][j] = (f32x4){0.f, 0.f, 0.f, 0.f};

    int srow = (lane >> 2);
    int sce  = (lane & 3) * 8;

    for (int k0 = 0; k0 < K; k0 += 32) {
        #pragma unroll
        for (int i = 0; i < 2; i++) {
            int seg = wave * 2 + i;
            int row = seg * 16 + srow;
            GLDS16(&A[(size_t)(m0 + row) * K + k0 + sce], &As[0][0] + seg * 512);
            GLDS16(&BT[(size_t)(n0 + row) * K + k0 + sce], &Bs[0][0] + seg * 512);
        }
        __syncthreads();
        short8v a[4], b[4];
        #pragma unroll
        for (int i = 0; i < 4; i++) {
            a[i] = *(const short8v*)&As[wr + i * 16 + fr][fq * 8];
            b[i] = *(const short8v*)&Bs[wc + i * 16 + fr][fq * 8];
        }
        #pragma unroll
        for (int i = 0; i < 4; i++)
            #pragma unroll
            for (int j = 0; j < 4; j++)
                acc[i][j] = __builtin_amdgcn_mfma_f32_16x16x32_bf16(a[i], b[j], acc[i][j], 0, 0, 0);
        __syncthreads();
    }
    #pragma unroll
    for (int i = 0; i < 4; i++)
        #pragma unroll
        for (int j = 0; j < 4; j++)
            #pragma unroll
            for (int t = 0; t < 4; t++) {
                int row = m0 + wr + i * 16 + fq * 4 + t;
                int col = n0 + wc + j * 16 + fr;
                float val = acc[i][j][t];
                if (OUT_F32) ((float*)C)[(size_t)row * N + col] = val;
                else ((us*)C)[(size_t)row * N + col] = f2bf(val);
            }
}

// ---------------- per-chunk precompute (pre-swizzled outputs; unchanged r6) ----------------
__global__ __launch_bounds__(256) void chunk_pre(
    const us* __restrict__ QKVG, const float* __restrict__ beta,
    us* __restrict__ Wbuf, us* __restrict__ Ubuf,
    us* __restrict__ Pbuf, us* __restrict__ KTbuf)
{
    __shared__ us Ks[8192];
    __shared__ us KTs[8192];
    __shared__ us VT[8192];
    __shared__ us Tb[4096];
    __shared__ float Af[64][64];
    __shared__ float betas[64];

    int c = blockIdx.x, bh = blockIdx.y;
    int b = bh >> 2, h = bh & 3;
    int tid = threadIdx.x;
    int wv = tid >> 6, ln = tid & 63;
    int fr = ln & 15, fq = ln >> 4;
    int tok0 = b * SEQ + c * 64;
    size_t cb = (size_t)bh * NCHUNK + c;

    #pragma unroll
    for (int r = 0; r < 4; r++) {
        int idx = tid + 256 * r;
        int t = idx >> 4, u = idx & 15;
        short8v kv = *(const short8v*)(QKVG + (size_t)(tok0 + t) * NPROJ + 512 + h * 128 + u * 8);
        *(short8v*)(Ks + sw16(t, u * 8)) = kv;
    }
    if (tid < 64) betas[tid] = beta[(size_t)(tok0 + tid) * 4 + h];
    __syncthreads();

    {   // L2-normalize K rows
        int t = tid >> 2, p = tid & 3;
        short8v v[4];
        float ss = 0.f;
        #pragma unroll
        for (int uu = 0; uu < 4; uu++) {
            v[uu] = *(const short8v*)(Ks + sw16(t, (p * 4 + uu) * 8));
            #pragma unroll
            for (int e = 0; e < 8; e++) {
                float f = bf2f((unsigned short)v[uu][e]);
                ss += f * f;
            }
        }
        ss += __shfl_xor(ss, 1);
        ss += __shfl_xor(ss, 2);
        float rn = rsqrtf(ss + 1e-12f);
        #pragma unroll
        for (int uu = 0; uu < 4; uu++) {
            short8v o;
            #pragma unroll
            for (int e = 0; e < 8; e++)
                o[e] = (short)f2bf(bf2f((unsigned short)v[uu][e]) * rn);
            *(short8v*)(Ks + sw16(t, (p * 4 + uu) * 8)) = o;
        }
    }
    __syncthreads();

    {   // A = strict_tril(beta_t K K^T)
        f32x4 aacc[4];
        #pragma unroll
        for (int jt = 0; jt < 4; jt++) aacc[jt] = (f32x4){0.f, 0.f, 0.f, 0.f};
        #pragma unroll
        for (int ks = 0; ks < 4; ks++) {
            short8v ak = *(const short8v*)(Ks + sw16(16 * wv + fr, 32 * ks + 8 * fq));
            #pragma unroll
            for (int jt = 0; jt < 4; jt++) {
                short8v bk = *(const short8v*)(Ks + sw16(16 * jt + fr, 32 * ks + 8 * fq));
                aacc[jt] = __builtin_amdgcn_mfma_f32_16x16x32_bf16(ak, bk, aacc[jt], 0, 0, 0);
            }
        }
        #pragma unroll
        for (int jt = 0; jt < 4; jt++)
            #pragma unroll
            for (int r = 0; r < 4; r++) {
                int t = 16 * wv + 4 * fq + r, s = 16 * jt + fr;
                if (s < t) Af[t][s] = betas[t] * aacc[jt][r];
            }
    }
    __syncthreads();

    if (wv == 0) {   // wave0: T = (I+A)^{-1}
        int cc = ln;
        for (int t = 1; t < 64; t++) {
            float aown = Af[t][cc];
            float acc = 0.f;
            for (int s = cc + 1; s < t; s++)
                acc += Af[t][s] * Af[s][cc];
            if (cc < t) Af[t][cc] = -aown - acc;
        }
    } else {         // waves 1-3: K^T, V^T(half0) scatters
        int q = tid - 64;
        for (int g = q; g < 1024; g += 192) {
            int t = g >> 4, u = g & 15;
            short8v kv = *(const short8v*)(Ks + sw16(t, u * 8));
            #pragma unroll
            for (int e = 0; e < 8; e++)
                KTs[sw8(u * 8 + e, t)] = (unsigned short)kv[e];
        }
        for (int g = q; g < 1024; g += 192) {
            int t = g >> 4, jg = g & 15;
            short8v vv = *(const short8v*)(QKVG + (size_t)(tok0 + t) * NPROJ + 1024 + h * 256 + jg * 8);
            #pragma unroll
            for (int e = 0; e < 8; e++)
                VT[sw8(jg * 8 + e, t)] = (unsigned short)vv[e];
        }
    }
    __syncthreads();

    {   // P = SC*tril(QK^T), Tb, KTbuf image copy
        f32x4 pacc[4];
        #pragma unroll
        for (int jt = 0; jt < 4; jt++) pacc[jt] = (f32x4){0.f, 0.f, 0.f, 0.f};
        #pragma unroll
        for (int ks = 0; ks < 4; ks++) {
            short8v aq = *(const short8v*)(QKVG + (size_t)(tok0 + 16 * wv + fr) * NPROJ + h * 128 + ks * 32 + fq * 8);
            #pragma unroll
            for (int jt = 0; jt < 4; jt++) {
                short8v bk = *(const short8v*)(Ks + sw16(16 * jt + fr, 32 * ks + 8 * fq));
                pacc[jt] = __builtin_amdgcn_mfma_f32_16x16x32_bf16(aq, bk, pacc[jt], 0, 0, 0);
            }
        }
        #pragma unroll
        for (int jt = 0; jt < 4; jt++)
            #pragma unroll
            for (int r = 0; r < 4; r++) {
                int t = 16 * wv + 4 * fq + r, s = 16 * jt + fr;
                float val = (s <= t) ? pacc[jt][r] * SCQ : 0.f;
                Pbuf[cb * 4096 + sw64(t, s)] = f2bf(val);
            }
        #pragma unroll
        for (int i = 0; i < 16; i++) {
            int idx = tid + 256 * i;
            int t = idx >> 6, s = idx & 63;
            float tv = (s < t) ? Af[t][s] : (s == t ? 1.f : 0.f);
            Tb[sw8(t, s)] = f2bf(tv * betas[s]);
        }
        #pragma unroll
        for (int i = 0; i < 4; i++) {
            int idx = tid + 256 * i;
            *(short8v*)(KTbuf + cb * 8192 + (size_t)idx * 8) =
                *(const short8v*)(KTs + (size_t)idx * 8);
        }
    }
    __syncthreads();

    {   // W = -(T'K), U half0
        f32x4 wacc[8], uacc[8];
        #pragma unroll
        for (int jt = 0; jt < 8; jt++) {
            wacc[jt] = (f32x4){0.f, 0.f, 0.f, 0.f};
            uacc[jt] = (f32x4){0.f, 0.f, 0.f, 0.f};
        }
        #pragma unroll
        for (int ks = 0; ks < 2; ks++) {
            short8v at = *(const short8v*)(Tb + sw8(16 * wv + fr, 32 * ks + 8 * fq));
            #pragma unroll
            for (int jt = 0; jt < 8; jt++) {
                short8v bk = *(const short8v*)(KTs + sw8(16 * jt + fr, 32 * ks + 8 * fq));
                wacc[jt] = __builtin_amdgcn_mfma_f32_16x16x32_bf16(at, bk, wacc[jt], 0, 0, 0);
                short8v bv = *(const short8v*)(VT + sw8(16 * jt + fr, 32 * ks + 8 * fq));
                uacc[jt] = __builtin_amdgcn_mfma_f32_16x16x32_bf16(at, bv, uacc[jt], 0, 0, 0);
            }
        }
        #pragma unroll
        for (int jt = 0; jt < 8; jt++)
            #pragma unroll
            for (int r = 0; r < 4; r++) {
                int t = 16 * wv + 4 * fq + r, d = 16 * jt + fr;
                Wbuf[cb * 8192 + sw128(t, d)] = f2bf(-wacc[jt][r]);
                Ubuf[cb * 16384 + swU(t, d)] = f2bf(uacc[jt][r]);
            }
    }
    __syncthreads();

    #pragma unroll
    for (int i = 0; i < 4; i++) {   // restage V^T half1
        int g = tid + 256 * i;
        int t = g >> 4, jg = g & 15;
        short8v vv = *(const short8v*)(QKVG + (size_t)(tok0 + t) * NPROJ + 1024 + h * 256 + 128 + jg * 8);
        #pragma unroll
        for (int e = 0; e < 8; e++)
            VT[sw8(jg * 8 + e, t)] = (unsigned short)vv[e];
    }
    __syncthreads();
    {
        f32x4 uacc[8];
        #pragma unroll
        for (int jt = 0; jt < 8; jt++) uacc[jt] = (f32x4){0.f, 0.f, 0.f, 0.f};
        #pragma unroll
        for (int ks = 0; ks < 2; ks++) {
            short8v at = *(const short8v*)(Tb + sw8(16 * wv + fr, 32 * ks + 8 * fq));
            #pragma unroll
            for (int jt = 0; jt < 8; jt++) {
                short8v bv = *(const short8v*)(VT + sw8(16 * jt + fr, 32 * ks + 8 * fq));
                uacc[jt] = __builtin_amdgcn_mfma_f32_16x16x32_bf16(at, bv, uacc[jt], 0, 0, 0);
            }
        }
        #pragma unroll
        for (int jt = 0; jt < 8; jt++)
            #pragma unroll
            for (int r = 0; r < 4; r++) {
                int t = 16 * wv + 4 * fq + r, j = 16 * jt + fr;
                Ubuf[cb * 16384 + swU(t, 128 + j)] = f2bf(uacc[jt][r]);
            }
    }
}

// ---------------- serial scan: SINGLE WAVE per (bh, 16-j slice); barrier-free ----------------
// LDS (elems): dbuf{ W 8192 | KT 8192 | U 1024 } x2 + ST 2048 + DT 1024 = 37888 (75776 B)
#define SCW 0
#define SCKT 8192
#define SCU 16384
#define SCBUF 17408
#define SCST (2 * SCBUF)
#define SCDT (2 * SCBUF + 2048)

__global__ __launch_bounds__(64, 1) void scan_mfma(
    const us* __restrict__ Wbuf, const us* __restrict__ Ubuf,
    const us* __restrict__ KTbuf, us* __restrict__ Sbuf)
{
    extern __shared__ us lds[];
    int ln = threadIdx.x;
    int fr = ln & 15, fq = ln >> 4;
    int sl = blockIdx.x;           // 0..15, 16 j-columns each
    int j0 = sl * 16;
    int bh = blockIdx.y;

    short8v id0;
    #pragma unroll
    for (int e = 0; e < 8; e++)
        id0[e] = (short)((8 * fq + e == fr) ? 0x3F80 : 0);

    f32x4 sacc[8];   // S[d=16*dt+4fq+r][j=fr(local)] for dt=0..7
    #pragma unroll
    for (int i = 0; i < 8; i++) sacc[i] = (f32x4){0.f, 0.f, 0.f, 0.f};

    auto issue = [&](int c1) {
        size_t cb = (size_t)bh * NCHUNK + c1;
        us* dst = lds + (c1 & 1) * SCBUF;
        const us* Wc = Wbuf + cb * 8192;
        const us* Kc = KTbuf + cb * 8192;
        #pragma unroll
        for (int i = 0; i < 16; i++) {
            GLDS16(Wc + i * 512 + ln * 8, dst + SCW + i * 512);
            GLDS16(Kc + i * 512 + ln * 8, dst + SCKT + i * 512);
        }
        const us* Uc = Ubuf + cb * 16384;
        #pragma unroll
        for (int i = 0; i < 2; i++) {
            int t = i * 32 + (ln >> 1);
            GLDS16(Uc + swU(t, j0 + (ln & 1) * 8), dst + SCU + i * 512);
        }
    };

    issue(0);
    asm volatile("s_waitcnt vmcnt(0)" ::: "memory");
    __builtin_amdgcn_sched_barrier(0);

    for (int c = 0; c < NCHUNK; c++) {
        const us* ba = lds + (c & 1) * SCBUF;

        // 1. write S^T (pre-update state) into private ST [16j][128d]
        #pragma unroll
        for (int dt = 0; dt < 8; dt++) {
            uint2 w;
            w.x = cvtpk(sacc[dt][0], sacc[dt][1]);
            w.y = cvtpk(sacc[dt][2], sacc[dt][3]);
            int col = 16 * dt + 4 * fq;
            int u = col >> 3;
            *(uint2*)&lds[SCST + fr * 128 + ((u ^ fr) & 15) * 8 + (col & 7)] = w;
        }
        // 2. prefetch next chunk (stays in flight, counted gate below)
        if (c + 1 < NCHUNK) issue(c + 1);
        // 3. dump ST image -> Sbuf (coalesced; raw swizzled image copy)
        {
            size_t sb = ((size_t)bh * NCHUNK + c) * 32768 + (size_t)j0 * 128;
            #pragma unroll
            for (int q = 0; q < 4; q++) {
                short8v v = *(const short8v*)&lds[SCST + q * 512 + ln * 8];
                *(short8v*)(Sbuf + sb + q * 512 + ln * 8) = v;
            }
        }
        // 4. gate: chunk c's 34 loads done (34 gld_{c+1} + 4 stores_c may remain)
        asm volatile("s_waitcnt vmcnt(38)" ::: "memory");
        __builtin_amdgcn_sched_barrier(0);

        // 5. Delta = U + (-W)*S : C[t][j]
        f32x4 dacc[4];
        #pragma unroll
        for (int tt = 0; tt < 4; tt++) dacc[tt] = (f32x4){0.f, 0.f, 0.f, 0.f};
        #pragma unroll
        for (int kc = 0; kc < 4; kc++) {
            short8v bs = *(const short8v*)&lds[SCST + fr * 128 + (((4 * kc + fq) ^ fr) & 15) * 8];
            #pragma unroll
            for (int tt = 0; tt < 4; tt++) {
                short8v aw = *(const short8v*)&ba[SCW + sw128(16 * tt + fr, 32 * kc + 8 * fq)];
                dacc[tt] = __builtin_amdgcn_mfma_f32_16x16x32_bf16(aw, bs, dacc[tt], 0, 0, 0);
            }
        }
        #pragma unroll
        for (int tt = 0; tt < 4; tt++) {
            short8v au = *(const short8v*)&ba[SCU + (16 * tt + fr) * 16 + 8 * (fq & 1)];
            dacc[tt] = __builtin_amdgcn_mfma_f32_16x16x32_bf16(au, id0, dacc[tt], 0, 0, 0);
        }
        // 6. Delta^T -> DT [16j][64t]; S += K^T * Delta
        #pragma unroll
        for (int tt = 0; tt < 4; tt++) {
            uint2 w;
            w.x = cvtpk(dacc[tt][0], dacc[tt][1]);
            w.y = cvtpk(dacc[tt][2], dacc[tt][3]);
            int col = 16 * tt + 4 * fq;
            int u = col >> 3;
            *(uint2*)&lds[SCDT + fr * 64 + ((u ^ fr) & 7) * 8 + (col & 7)] = w;
        }
        short8v bd[2];
        #pragma unroll
        for (int kc = 0; kc < 2; kc++)
            bd[kc] = *(const short8v*)&lds[SCDT + fr * 64 + (((4 * kc + fq) ^ fr) & 7) * 8];
        #pragma unroll
        for (int kc = 0; kc < 2; kc++)
            #pragma unroll
            for (int dt = 0; dt < 8; dt++) {
                short8v ak = *(const short8v*)&ba[SCKT + sw64(16 * dt + fr, 32 * kc + 8 * fq)];
                sacc[dt] = __builtin_amdgcn_mfma_f32_16x16x32_bf16(ak, bd[kc], sacc[dt], 0, 0, 0);
            }
    }
}

// ---------------- parallel output: O = SCQ*Q*S-hat + P*(U - W*S-hat) ----------------
#define K2_W 0
#define K2_P 8192
#define K2_U 12288
#define K2_S 20480
#define K2_Q 36864
#define K2_DT 45056
// total 53248 elems = 106496 B

__global__ __launch_bounds__(256, 1) void out_k(
    const us* __restrict__ QKVG, const us* __restrict__ Wbuf,
    const us* __restrict__ Ubuf, const us* __restrict__ Pbuf,
    const us* __restrict__ Sbuf, us* __restrict__ Ob)
{
    extern __shared__ us lds[];
    int tid = threadIdx.x;
    int wv = tid >> 6, ln = tid & 63;
    int fr = ln & 15, fq = ln >> 4;
    int c = blockIdx.x;
    int bh = blockIdx.y >> 1, jh = blockIdx.y & 1;
    int b = bh >> 2, h = bh & 3;
    int tok0 = b * SEQ + c * 64;
    size_t cb = (size_t)bh * NCHUNK + c;

    short8v id0, id1;
    #pragma unroll
    for (int e = 0; e < 8; e++) {
        id0[e] = (short)((8 * fq + e == fr) ? 0x3F80 : 0);
        id1[e] = (short)((8 * fq + e == fr + 16) ? 0x3F80 : 0);
    }

    #pragma unroll
    for (int i = 0; i < 4; i++) {
        int q = (i * 4 + wv) * 512 + ln * 8;
        GLDS16(Wbuf + cb * 8192 + q, lds + K2_W + (i * 4 + wv) * 512);
    }
    #pragma unroll
    for (int i = 0; i < 2; i++) {
        int q = (i * 4 + wv) * 512 + ln * 8;
        GLDS16(Pbuf + cb * 4096 + q, lds + K2_P + (i * 4 + wv) * 512);
    }
    #pragma unroll
    for (int i = 0; i < 4; i++) {
        int q = (i * 4 + wv) * 512 + ln * 8;
        int t = q >> 7, r = q & 127;
        GLDS16(Ubuf + cb * 16384 + t * 256 + jh * 128 + r, lds + K2_U + (i * 4 + wv) * 512);
    }
    size_t sbase = ((size_t)cb * 4 + jh * 2) * 8192;
    #pragma unroll
    for (int i = 0; i < 8; i++) {
        int q = (i * 4 + wv) * 512 + ln * 8;
        GLDS16(Sbuf + sbase + q, lds + K2_S + (i * 4 + wv) * 512);
    }
    short8v qv[4];
    #pragma unroll
    for (int i = 0; i < 4; i++) {
        int idx = tid + 256 * i;
        int t = idx >> 4, u = idx & 15;
        qv[i] = *(const short8v*)(QKVG + (size_t)(tok0 + t) * NPROJ + h * 128 + u * 8);
    }
    #pragma unroll
    for (int i = 0; i < 4; i++) {
        int idx = tid + 256 * i;
        int t = idx >> 4, u = idx & 15;
        *(short8v*)&lds[K2_Q + sw128(t, u * 8)] = qv[i];
    }
    __syncthreads();

    f32x4 dacc[8], oacc[8];
    #pragma unroll
    for (int jt = 0; jt < 8; jt++) {
        dacc[jt] = (f32x4){0.f, 0.f, 0.f, 0.f};
        oacc[jt] = (f32x4){0.f, 0.f, 0.f, 0.f};
    }
    #pragma unroll
    for (int ks = 0; ks < 4; ks++) {
        short8v aw = *(const short8v*)&lds[K2_W + sw128(16 * wv + fr, 32 * ks + 8 * fq)];
        short8v aq = *(const short8v*)&lds[K2_Q + sw128(16 * wv + fr, 32 * ks + 8 * fq)];
        #pragma unroll
        for (int jt = 0; jt < 8; jt++) {
            int j = 16 * jt + fr;
            short8v bs = *(const short8v*)&lds[K2_S + (j >> 6) * 8192 + swST(j & 63, 32 * ks + 8 * fq)];
            dacc[jt] = __builtin_amdgcn_mfma_f32_16x16x32_bf16(aw, bs, dacc[jt], 0, 0, 0);
            oacc[jt] = __builtin_amdgcn_mfma_f32_16x16x32_bf16(aq, bs, oacc[jt], 0, 0, 0);
        }
    }
    #pragma unroll
    for (int ju = 0; ju < 4; ju++) {
        short8v au = *(const short8v*)&lds[K2_U + swU128(16 * wv + fr, 32 * ju + 8 * fq)];
        dacc[2 * ju + 0] = __builtin_amdgcn_mfma_f32_16x16x32_bf16(au, id0, dacc[2 * ju + 0], 0, 0, 0);
        dacc[2 * ju + 1] = __builtin_amdgcn_mfma_f32_16x16x32_bf16(au, id1, dacc[2 * ju + 1], 0, 0, 0);
    }
    #pragma unroll
    for (int jt = 0; jt < 8; jt++)
        #pragma unroll
        for (int r = 0; r < 4; r++) oacc[jt][r] *= SCQ;
    #pragma unroll
    for (int jt = 0; jt < 8; jt++) {
        int j = 16 * jt + fr;
        int t0 = 16 * wv + 4 * fq;
        uint2 w;
        w.x = cvtpk(dacc[jt][0], dacc[jt][1]);
        w.y = cvtpk(dacc[jt][2], dacc[jt][3]);
        *(uint2*)&lds[K2_DT + sw64(j, t0)] = w;
    }
    bar_lgkm();

    #pragma unroll
    for (int ks = 0; ks < 2; ks++) {
        short8v ap = *(const short8v*)&lds[K2_P + sw64(16 * wv + fr, 32 * ks + 8 * fq)];
        #pragma unroll
        for (int jt = 0; jt < 8; jt++) {
            short8v bd = *(const short8v*)&lds[K2_DT + sw64(16 * jt + fr, 32 * ks + 8 * fq)];
            oacc[jt] = __builtin_amdgcn_mfma_f32_16x16x32_bf16(ap, bd, oacc[jt], 0, 0, 0);
        }
    }
    us* ob = Ob + (size_t)tok0 * 1024 + h * 256 + jh * 128;
    #pragma unroll
    for (int jt = 0; jt < 8; jt++)
        #pragma unroll
        for (int r = 0; r < 4; r++) {
            int t = 16 * wv + 4 * fq + r;
            ob[(size_t)t * 1024 + 16 * jt + fr] = f2bf(oacc[jt][r]);
        }
}

// ---------------- RMSNorm + swish gate ----------------
__global__ __launch_bounds__(256) void gate_norm(const us* __restrict__ Ob,
                                                 const us* __restrict__ QKVG,
                                                 const float* __restrict__ norm_w,
                                                 us* __restrict__ o2)
{
    int gid = blockIdx.x * 4 + (threadIdx.x >> 6);
    int ln = threadIdx.x & 63;
    int tok = gid >> 2, h = gid & 3;
    size_t base = (size_t)tok * 1024 + h * 256 + ln * 4;
    uint2 ov = *(const uint2*)&Ob[base];
    float o0 = bf2f((us)ov.x), o1 = bf2f((us)(ov.x >> 16));
    float o2v = bf2f((us)ov.y), o3 = bf2f((us)(ov.y >> 16));
    float ss = o0 * o0 + o1 * o1 + o2v * o2v + o3 * o3;
    #pragma unroll
    for (int off = 32; off; off >>= 1) ss += __shfl_xor(ss, off);
    float r = rsqrtf(ss * (1.0f / 256.0f) + 1e-5f);
    uint2 gv = *(const uint2*)&QKVG[(size_t)tok * NPROJ + 2048 + h * 256 + ln * 4];
    float g0 = bf2f((us)gv.x), g1 = bf2f((us)(gv.x >> 16));
    float g2 = bf2f((us)gv.y), g3 = bf2f((us)(gv.y >> 16));
    float4 nw = *(const float4*)&norm_w[ln * 4];
    float r0 = o0 * r * nw.x * (g0 / (1.f + __expf(-g0)));
    float r1 = o1 * r * nw.y * (g1 / (1.f + __expf(-g1)));
    float r2 = o2v * r * nw.z * (g2 / (1.f + __expf(-g2)));
    float r3 = o3 * r * nw.w * (g3 / (1.f + __expf(-g3)));
    uint2 w;
    w.x = cvtpk(r0, r1);
    w.y = cvtpk(r2, r3);
    *(uint2*)&o2[base] = w;
}

// ---------------- launch ----------------
extern "C" void kernel_launch(void* const* d_in, const int* in_sizes, int n_in,
                              void* d_out, int out_size, void* d_ws, size_t ws_size,
                              hipStream_t stream) {
    const float* x      = (const float*)d_in[0];
    const float* Wq     = (const float*)d_in[1];
    const float* Wk     = (const float*)d_in[2];
    const float* Wv     = (const float*)d_in[3];
    const float* Wb     = (const float*)d_in[4];
    const float* Wg     = (const float*)d_in[5];
    const float* Wo     = (const float*)d_in[6];
    const float* norm_w = (const float*)d_in[7];
    float* out = (float*)d_out;

    char* ws = (char*)d_ws;
    us*    xb   = (us*)(ws + 0);            // 16 MB
    us*    WT   = (us*)(ws + 16777216);     //  6 MB
    us*    Sbuf = (us*)(ws + 0);            // 32 MB (alias xb+WT, dead after gemm0)
    us*    KTbuf= (us*)(ws + 33554432);     //  8 MB
    us*    Ob   = (us*)(ws + 33554432);     // 16 MB (alias KTbuf, dead after scan)
    us*    QKVG = (us*)(ws + 50331648);     // 48 MB
    float* beta = (float*)(ws + 100663296); // 128 KB
    us*    Wbuf = (us*)(ws + 100794368);    //  8 MB
    us*    Ubuf = (us*)(ws + 109182976);    // 16 MB
    us*    o2   = (us*)(ws + 109182976);    // (alias Ubuf, dead after out_k)
    us*    Pbuf = (us*)(ws + 125960192);    //  4 MB
    us*    WoT  = (us*)(ws + 130154496);    //  2 MB

    (void)hipFuncSetAttribute((const void*)scan_mfma,
                              hipFuncAttributeMaxDynamicSharedMemorySize, 75776);
    (void)hipFuncSetAttribute((const void*)out_k,
                              hipFuncAttributeMaxDynamicSharedMemorySize, 106496);

    convert_x<<<(NTOK * DM / 4 + 255) / 256, 256, 0, stream>>>(x, xb, NTOK * DM / 4);
    transpose_w<<<dim3(8, 16), 256, 0, stream>>>(Wq, WT, DM, 512);
    transpose_w<<<dim3(8, 16), 256, 0, stream>>>(Wk, WT + (size_t)512 * DM, DM, 512);
    transpose_w<<<dim3(16, 16), 256, 0, stream>>>(Wv, WT + (size_t)1024 * DM, DM, 1024);
    transpose_w<<<dim3(16, 16), 256, 0, stream>>>(Wg, WT + (size_t)2048 * DM, DM, 1024);
    transpose_w<<<dim3(16, 16), 256, 0, stream>>>(Wo, WoT, DM, 1024);
    beta_kernel<<<NTOK / 16, 256, 0, stream>>>(x, Wb, beta);
    gemm_bt<0><<<dim3(64, 24), 256, 0, stream>>>(xb, WT, (void*)QKVG, NTOK, NPROJ, DM);
    chunk_pre<<<dim3(NCHUNK, 8), 256, 0, stream>>>(QKVG, beta, Wbuf, Ubuf, Pbuf, KTbuf);
    scan_mfma<<<dim3(16, 8), 64, 75776, stream>>>(Wbuf, Ubuf, KTbuf, Sbuf);
    out_k<<<dim3(NCHUNK, 16), 256, 106496, stream>>>(QKVG, Wbuf, Ubuf, Pbuf, Sbuf, Ob);
    gate_norm<<<NTOK, 256, 0, stream>>>(Ob, QKVG, norm_w, o2);
    gemm_bt<1><<<dim3(64, 8), 256, 0, stream>>>(o2, WoT, (void*)out, NTOK, DM, DM);
}